// Round 5
// baseline (1013.662 us; speedup 1.0000x reference)
//
#include <hip/hip_runtime.h>

typedef unsigned int u32;
typedef unsigned short u16;

#define Bn 16
#define Nn 1024
#define Pp 72

#define NEGINF __int_as_float(0xff800000)

// ---------- helpers ----------
__device__ __forceinline__ float wsumf(float v) {
#pragma unroll
  for (int off = 1; off < 64; off <<= 1) v += __shfl_xor(v, off, 64);
  return v;
}
__device__ __forceinline__ float wmaxf(float v) {
#pragma unroll
  for (int off = 1; off < 64; off <<= 1) v = fmaxf(v, __shfl_xor(v, off, 64));
  return v;
}
__device__ __forceinline__ u32 wminu(u32 v) {
#pragma unroll
  for (int off = 1; off < 64; off <<= 1) {
    u32 o = (u32)__shfl_xor((int)v, off, 64);
    v = (o < v) ? o : v;
  }
  return v;
}

// ---------- kernel 1: fused mean-over-P + node MLP (fp64) ----------
// one block (128 thr) per (b,n); emits dyn_emb fp64 into d_out scratch
__global__ __launch_bounds__(128) void k_meanmlp(const float* __restrict__ pf,
                                                 const float* __restrict__ dW1,
                                                 const float* __restrict__ db1,
                                                 const float* __restrict__ ln_g,
                                                 const float* __restrict__ ln_b,
                                                 const float* __restrict__ dW2,
                                                 const float* __restrict__ db2,
                                                 double* __restrict__ embD) {
  __shared__ double ndD[96];
  __shared__ double red[64];
  __shared__ double h1r[64];
  const int t = threadIdx.x;
  const int bn = blockIdx.x;

  if (t < 96) {
    const float* src = pf + (size_t)bn * (Pp * 96) + t;
    double s = 0.0;
    for (int p = 0; p < Pp; ++p) s += (double)src[p * 96];
    ndD[t] = s / 72.0;
  }
  __syncthreads();

  double a = 0.0;
  if (t < 64) {
    a = (double)db1[t];
    for (int d = 0; d < 96; ++d) a = fma(ndD[d], (double)dW1[d * 64 + t], a);
    red[t] = a;
  }
  __syncthreads();
  for (int s2 = 32; s2 >= 1; s2 >>= 1) {
    if (t < s2) red[t] += red[t + s2];
    __syncthreads();
  }
  const double mu = red[0] * (1.0 / 64.0);
  __syncthreads();
  const double dv = a - mu;
  if (t < 64) red[t] = dv * dv;
  __syncthreads();
  for (int s2 = 32; s2 >= 1; s2 >>= 1) {
    if (t < s2) red[t] += red[t + s2];
    __syncthreads();
  }
  const double var = red[0] * (1.0 / 64.0);
  if (t < 64) {
    double xn = dv / sqrt(var + 1e-5) * (double)ln_g[t] + (double)ln_b[t];
    h1r[t] = xn > 0.0 ? xn : 0.0;
  }
  __syncthreads();
  if (t < 64) {
    double e = (double)db2[t];
    for (int k = 0; k < 64; ++k) e = fma(h1r[k], (double)dW2[k * 64 + t], e);
    embD[(size_t)bn * 64 + t] = e;
  }
}

// ---------- kernel 2/3: graph rows, fp64 logits, exact top-16, fp32 out ----------
// MODE 0: static (E1 fp32 rows). MODE 1: dynamic (embD fp64 rows).
template <int MODE>
__global__ __launch_bounds__(256) void k_rows(const float* __restrict__ e1f,
                                              const double* __restrict__ embD,
                                              const float* __restrict__ E2,
                                              const float* __restrict__ temp,
                                              float* __restrict__ outp) {
  __shared__ float lgA[8][1024];  // hi of Dekker pair; later reused for fp32 out
  __shared__ float lgB[8][1024];  // lo of Dekker pair
  const int t = threadIdx.x;
  const int r0 = blockIdx.x * 8;  // 8 rows per block, all same head
  int h;
  const float* ef = nullptr;
  const double* ed = nullptr;
  if (MODE == 0) {
    h = r0 >> 10;
    ef = e1f + (size_t)r0 * 64;
  } else {
    int b = r0 >> 12;
    h = (r0 >> 10) & 3;
    int n0 = r0 & 1023;
    ed = embD + ((size_t)(b << 10) + n0) * 64;
  }
  const float4* e2 = (const float4*)(E2 + (size_t)h * (64 * 1024));
  const double Td = (double)temp[h];

  // ---- dot phase (fp64): thread t owns cols 4t..4t+3 for all 8 rows ----
  double acc[8][4];
#pragma unroll
  for (int g = 0; g < 8; ++g)
#pragma unroll
    for (int x = 0; x < 4; ++x) acc[g][x] = 0.0;

  for (int d = 0; d < 64; ++d) {
    float4 ev = e2[d * 256 + t];
    double dx = (double)ev.x, dy = (double)ev.y, dz = (double)ev.z, dw = (double)ev.w;
#pragma unroll
    for (int g = 0; g < 8; ++g) {
      double s = (MODE == 0) ? (double)ef[g * 64 + d] : ed[g * 64 + d];
      acc[g][0] = fma(s, dx, acc[g][0]);
      acc[g][1] = fma(s, dy, acc[g][1]);
      acc[g][2] = fma(s, dz, acc[g][2]);
      acc[g][3] = fma(s, dw, acc[g][3]);
    }
  }
#pragma unroll
  for (int g = 0; g < 8; ++g) {
    float4 hv, lv;
    {
      double q = (acc[g][0] > 0.0 ? acc[g][0] : 0.0) / Td;
      hv.x = (float)q; lv.x = (float)(q - (double)hv.x);
      q = (acc[g][1] > 0.0 ? acc[g][1] : 0.0) / Td;
      hv.y = (float)q; lv.y = (float)(q - (double)hv.y);
      q = (acc[g][2] > 0.0 ? acc[g][2] : 0.0) / Td;
      hv.z = (float)q; lv.z = (float)(q - (double)hv.z);
      q = (acc[g][3] > 0.0 ? acc[g][3] : 0.0) / Td;
      hv.w = (float)q; lv.w = (float)(q - (double)hv.w);
    }
    ((float4*)(&lgA[g][0]))[t] = hv;
    ((float4*)(&lgB[g][0]))[t] = lv;
  }
  __syncthreads();

  // ---- selection: wave w handles rows 2w,2w+1; lane l owns cols l+64j ----
  const int w = t >> 6, l = t & 63;

#pragma unroll 1
  for (int gi = 0; gi < 2; ++gi) {
    const int g = w * 2 + gi;
    double qd[16];
#pragma unroll
    for (int j = 0; j < 16; ++j)
      qd[j] = (double)lgA[g][l + (j << 6)] + (double)lgB[g][l + (j << 6)];

    // wave max (qmax) via (hi,lo) 2-phase 32-bit reduction
    double bm = qd[0];
#pragma unroll
    for (int j = 1; j < 16; ++j) bm = qd[j] > bm ? qd[j] : bm;
    float mh = (float)bm;
    float mlo = (float)(bm - (double)mh);
    float whi = wmaxf(mh);
    float wlo = wmaxf(mh == whi ? mlo : NEGINF);
    const double qmaxd = (double)whi + (double)wlo;

    float e[16];
    float es = 0.0f;
#pragma unroll
    for (int j = 0; j < 16; ++j) { e[j] = __expf((float)(qd[j] - qmaxd)); es += e[j]; }
    const float Z = wsumf(es);  // full softmax denominator (for 1e-8*Z term)

    // exact top-16: (hi,lo) float-pair lex order == fp64 order; ties -> min index
    u32 kept = 0;
    float EK = 0.0f;
#pragma unroll 1
    for (int it = 0; it < 16; ++it) {
      double bv = -1.0;
      int bjj = -1;
#pragma unroll
      for (int j = 0; j < 16; ++j) {
        bool tk = (((kept >> j) & 1u) == 0u) && (qd[j] > bv);
        bv = tk ? qd[j] : bv;
        bjj = tk ? j : bjj;
      }
      float bh = NEGINF, bl = NEGINF;
      if (bjj >= 0) { bh = (float)bv; bl = (float)(bv - (double)bh); }
      float vhi = wmaxf(bh);
      float vlo = wmaxf(bh == vhi ? bl : NEGINF);
      bool elig = (bh == vhi) && (bl == vlo);
      u32 mc = elig ? (u32)((bjj << 6) | l) : 0xFFFFFFFFu;
      u32 mwin = wminu(mc);
      EK += __expf((float)(((double)vhi + (double)vlo) - qmaxd));
      if ((mwin & 63u) == (u32)l) kept |= 1u << (mwin >> 6);
    }
    const float inv = 1.0f / (EK + 1e-8f * Z);
    // fp32 sparse row back into lgA[g] (each lane rewrites only its own cols)
#pragma unroll
    for (int j = 0; j < 16; ++j) {
      float sv = ((kept >> j) & 1u) ? (e[j] * inv) : 0.0f;
      lgA[g][l + (j << 6)] = sv;
    }
  }
  __syncthreads();

  // ---- coalesced flush: 8 rows x 1024 fp32 ----
  float4* gout = (float4*)(outp + (size_t)r0 * 1024);
  const float4* src = (const float4*)(&lgA[0][0]);
#pragma unroll
  for (int k = 0; k < 8; ++k) {
    int i = t + k * 256;   // 2048 float4 = 8 rows x 1024 floats
    gout[i] = src[i];
  }
}

// ---------- kernel 4: fuse + edge MLP + head mean + sigmoid (fp32 io) ----------
// Runs LAST; overwrites the d_out scratch region (embD) with final_adjs.
__global__ __launch_bounds__(256) void k_fuse(const float* __restrict__ dyn,
                                              const float* __restrict__ stat,
                                              float* __restrict__ fin,
                                              const float* __restrict__ eW1,
                                              const float* __restrict__ eb1,
                                              const float* __restrict__ eW2,
                                              const float* __restrict__ eb2,
                                              const float* __restrict__ fwp) {
  const float w = fwp[0];
  const float w1 = 1.0f - w;
  float W1[4][8], B1v[8], W2v[8];
#pragma unroll
  for (int hh = 0; hh < 4; ++hh)
#pragma unroll
    for (int j = 0; j < 8; ++j) W1[hh][j] = eW1[hh * 8 + j];
#pragma unroll
  for (int j = 0; j < 8; ++j) { B1v[j] = eb1[j]; W2v[j] = eW2[j]; }
  const float b2 = eb2[0];

  // one float4 (4 adjacent cols) of final per thread-iteration
  const int i = blockIdx.x * 256 + threadIdx.x;   // [0, 4194304)
  const int b = i >> 18;
  const int rem = i & 262143;
  const int n = rem >> 8;
  const int c4 = rem & 255;

  float fx[4][4];
#pragma unroll
  for (int hh = 0; hh < 4; ++hh) {
    float4 fd = ((const float4*)dyn)[(((size_t)((b * 4 + hh) * 1024 + n)) << 8) + c4];
    float4 fs = ((const float4*)stat)[(((size_t)(hh * 1024 + n)) << 8) + c4];
    fx[hh][0] = w1 * fs.x + w * fd.x;
    fx[hh][1] = w1 * fs.y + w * fd.y;
    fx[hh][2] = w1 * fs.z + w * fd.z;
    fx[hh][3] = w1 * fs.w + w * fd.w;
  }
  float ov[4];
#pragma unroll
  for (int x = 0; x < 4; ++x) {
    float ew = b2;
#pragma unroll
    for (int j = 0; j < 8; ++j) {
      float hj = B1v[j];
#pragma unroll
      for (int hh = 0; hh < 4; ++hh) hj = fmaf(fx[hh][x], W1[hh][j], hj);
      ew = fmaf(fmaxf(hj, 0.0f), W2v[j], ew);
    }
    float mean = (fx[0][x] + fx[1][x] + fx[2][x] + fx[3][x]) * 0.25f;
    float sg = 1.0f / (1.0f + __expf(-ew));
    ov[x] = sg * mean;
  }
  float4 o;
  o.x = ov[0]; o.y = ov[1]; o.z = ov[2]; o.w = ov[3];
  ((float4*)fin)[i] = o;
}

// ---------- launch ----------
extern "C" void kernel_launch(void* const* d_in, const int* in_sizes, int n_in,
                              void* d_out, int out_size, void* d_ws, size_t ws_size,
                              hipStream_t stream) {
  const float* pf   = (const float*)d_in[0];
  const float* E1   = (const float*)d_in[1];
  const float* E2   = (const float*)d_in[2];
  const float* temp = (const float*)d_in[3];
  const float* fw   = (const float*)d_in[4];
  const float* dW1  = (const float*)d_in[5];
  const float* db1  = (const float*)d_in[6];
  const float* ln_g = (const float*)d_in[7];
  const float* ln_b = (const float*)d_in[8];
  const float* dW2  = (const float*)d_in[9];
  const float* db2  = (const float*)d_in[10];
  const float* eW1  = (const float*)d_in[11];
  const float* eb1  = (const float*)d_in[12];
  const float* eW2  = (const float*)d_in[13];
  const float* eb2  = (const float*)d_in[14];

  // OUTPUTS ARE FLOAT32 (reference returns fp32; round-4 sentinel proved the
  // harness reads fp32 — bf16 writes altered nothing). Flat float layout:
  float* out_final = (float*)d_out;                              // 16,777,216 f
  float* out_stat  = out_final + (size_t)Bn * Nn * Nn;           // + 4,194,304 f
  float* out_dyn   = out_stat + (size_t)4 * Nn * Nn;             // +67,108,864 f

  // dyn_emb fp64 scratch inside the final region (8.4MB << 64MB); k_fuse
  // (launched last) overwrites it with the real final_adjs. Stream-ordered.
  double* embD = (double*)d_out;

  k_meanmlp<<<Bn * Nn, 128, 0, stream>>>(pf, dW1, db1, ln_g, ln_b, dW2, db2, embD);
  k_rows<0><<<512, 256, 0, stream>>>(E1, nullptr, E2, temp, out_stat);
  k_rows<1><<<8192, 256, 0, stream>>>(nullptr, embD, E2, temp, out_dyn);
  k_fuse<<<16384, 256, 0, stream>>>(out_dyn, out_stat, out_final, eW1, eb1, eW2, eb2, fw);
}

// Round 6
// 701.780 us; speedup vs baseline: 1.4444x; 1.4444x over previous
//
#include <hip/hip_runtime.h>

typedef unsigned int u32;
typedef unsigned short u16;

#define Bn 16
#define Nn 1024
#define Pp 72
#define MARG 3e-4f

#define NEGINF __int_as_float(0xff800000)
#define POSINF __int_as_float(0x7f800000)

// ---------- wave helpers ----------
__device__ __forceinline__ float wsumf(float v) {
#pragma unroll
  for (int off = 1; off < 64; off <<= 1) v += __shfl_xor(v, off, 64);
  return v;
}
__device__ __forceinline__ int wsumi(int v) {
#pragma unroll
  for (int off = 1; off < 64; off <<= 1) v += __shfl_xor(v, off, 64);
  return v;
}
__device__ __forceinline__ float wmaxf(float v) {
#pragma unroll
  for (int off = 1; off < 64; off <<= 1) v = fmaxf(v, __shfl_xor(v, off, 64));
  return v;
}
__device__ __forceinline__ float wminf(float v) {
#pragma unroll
  for (int off = 1; off < 64; off <<= 1) v = fminf(v, __shfl_xor(v, off, 64));
  return v;
}
__device__ __forceinline__ u32 wminu(u32 v) {
#pragma unroll
  for (int off = 1; off < 64; off <<= 1) {
    u32 o = (u32)__shfl_xor((int)v, off, 64);
    v = (o < v) ? o : v;
  }
  return v;
}

// ---------- kernel 0: E2 transpose (per head): E2T[h][m][d] = E2[h][d][m] ----------
__global__ __launch_bounds__(256) void k_e2t(const float* __restrict__ E2,
                                             float* __restrict__ E2T) {
  __shared__ float tile[32][65];
  const int h = blockIdx.x >> 5;
  const int m0 = (blockIdx.x & 31) << 5;
  const float* src = E2 + (size_t)h * 65536;
  float* dst = E2T + (size_t)h * 65536;
  const int t = threadIdx.x;
#pragma unroll
  for (int k = 0; k < 8; ++k) {
    int idx = k * 256 + t;
    int d = idx >> 5, mm = idx & 31;
    tile[mm][d] = src[d * 1024 + m0 + mm];
  }
  __syncthreads();
#pragma unroll
  for (int k = 0; k < 8; ++k) {
    int idx = k * 256 + t;
    int mm = idx >> 6, d = idx & 63;
    dst[(size_t)(m0 + mm) * 64 + d] = tile[mm][d];
  }
}

// ---------- kernel 1: fused mean-over-P + node MLP (fp64), emits fp64+fp32 ----------
__global__ __launch_bounds__(128) void k_meanmlp(const float* __restrict__ pf,
                                                 const float* __restrict__ dW1,
                                                 const float* __restrict__ db1,
                                                 const float* __restrict__ ln_g,
                                                 const float* __restrict__ ln_b,
                                                 const float* __restrict__ dW2,
                                                 const float* __restrict__ db2,
                                                 double* __restrict__ embD,
                                                 float* __restrict__ embF) {
  __shared__ double ndD[96];
  __shared__ double red[64];
  __shared__ double h1r[64];
  const int t = threadIdx.x;
  const int bn = blockIdx.x;

  if (t < 96) {
    const float* src = pf + (size_t)bn * (Pp * 96) + t;
    double s = 0.0;
    for (int p = 0; p < Pp; ++p) s += (double)src[p * 96];
    ndD[t] = s / 72.0;
  }
  __syncthreads();

  double a = 0.0;
  if (t < 64) {
    a = (double)db1[t];
    for (int d = 0; d < 96; ++d) a = fma(ndD[d], (double)dW1[d * 64 + t], a);
    red[t] = a;
  }
  __syncthreads();
  for (int s2 = 32; s2 >= 1; s2 >>= 1) {
    if (t < s2) red[t] += red[t + s2];
    __syncthreads();
  }
  const double mu = red[0] * (1.0 / 64.0);
  __syncthreads();
  const double dv = a - mu;
  if (t < 64) red[t] = dv * dv;
  __syncthreads();
  for (int s2 = 32; s2 >= 1; s2 >>= 1) {
    if (t < s2) red[t] += red[t + s2];
    __syncthreads();
  }
  const double var = red[0] * (1.0 / 64.0);
  if (t < 64) {
    double xn = dv / sqrt(var + 1e-5) * (double)ln_g[t] + (double)ln_b[t];
    h1r[t] = xn > 0.0 ? xn : 0.0;
  }
  __syncthreads();
  if (t < 64) {
    double e = (double)db2[t];
    for (int k = 0; k < 64; ++k) e = fma(h1r[k], (double)dW2[k * 64 + t], e);
    embD[(size_t)bn * 64 + t] = e;
    embF[(size_t)bn * 64 + t] = (float)e;
  }
}

// ---------- kernel 2/3: graph rows ----------
// fp32 dot -> bisection top-16 -> (rare) fp64 boundary rescore -> renorm -> fp32 out
// MODE 0: static (E1). MODE 1: dynamic (embF/embD).
template <int MODE>
__global__ __launch_bounds__(256) void k_rows(const float* __restrict__ e1f,
                                              const double* __restrict__ embD,
                                              const float* __restrict__ embF,
                                              const float* __restrict__ E2,
                                              const float* __restrict__ E2T,
                                              const float* __restrict__ temp,
                                              float* __restrict__ outp) {
  __shared__ float lgA[8][1024];   // fp32 logits, then fp32 output values
  __shared__ float embsh[64][8];   // emb staged [d][g]
  const int t = threadIdx.x;
  const int r0 = blockIdx.x * 8;   // 8 rows per block, same head
  int h;
  size_t erow;
  if (MODE == 0) {
    h = r0 >> 10;
    erow = (size_t)r0;
  } else {
    int b = r0 >> 12;
    h = (r0 >> 10) & 3;
    int n0 = r0 & 1023;
    erow = (size_t)(b << 10) + n0;
  }
  const float* efa = (MODE == 0) ? (e1f + erow * 64) : (embF + erow * 64);
  const float4* e2 = (const float4*)(E2 + (size_t)h * 65536);
  const float* e2t = E2T + (size_t)h * 65536;
  const float invT = 1.0f / temp[h];   // ranking-monotone; T=0.5 exact
  const double Td = (double)temp[h];

  // stage emb fp32 into LDS (transposed [d][g])
  for (int k = t; k < 512; k += 256) {
    int g = k & 7, d = k >> 3;
    embsh[d][g] = efa[g * 64 + d];
  }
  __syncthreads();

  // ---- phase A: fp32 dot; thread t owns cols 4t..4t+3 for all 8 rows ----
  float acc[8][4];
#pragma unroll
  for (int g = 0; g < 8; ++g)
#pragma unroll
    for (int x = 0; x < 4; ++x) acc[g][x] = 0.0f;

#pragma unroll 2
  for (int d = 0; d < 64; ++d) {
    float4 ev = e2[d * 256 + t];
    float4 sa = *(const float4*)&embsh[d][0];
    float4 sb = *(const float4*)&embsh[d][4];
    acc[0][0] = fmaf(sa.x, ev.x, acc[0][0]);
    acc[0][1] = fmaf(sa.x, ev.y, acc[0][1]);
    acc[0][2] = fmaf(sa.x, ev.z, acc[0][2]);
    acc[0][3] = fmaf(sa.x, ev.w, acc[0][3]);
    acc[1][0] = fmaf(sa.y, ev.x, acc[1][0]);
    acc[1][1] = fmaf(sa.y, ev.y, acc[1][1]);
    acc[1][2] = fmaf(sa.y, ev.z, acc[1][2]);
    acc[1][3] = fmaf(sa.y, ev.w, acc[1][3]);
    acc[2][0] = fmaf(sa.z, ev.x, acc[2][0]);
    acc[2][1] = fmaf(sa.z, ev.y, acc[2][1]);
    acc[2][2] = fmaf(sa.z, ev.z, acc[2][2]);
    acc[2][3] = fmaf(sa.z, ev.w, acc[2][3]);
    acc[3][0] = fmaf(sa.w, ev.x, acc[3][0]);
    acc[3][1] = fmaf(sa.w, ev.y, acc[3][1]);
    acc[3][2] = fmaf(sa.w, ev.z, acc[3][2]);
    acc[3][3] = fmaf(sa.w, ev.w, acc[3][3]);
    acc[4][0] = fmaf(sb.x, ev.x, acc[4][0]);
    acc[4][1] = fmaf(sb.x, ev.y, acc[4][1]);
    acc[4][2] = fmaf(sb.x, ev.z, acc[4][2]);
    acc[4][3] = fmaf(sb.x, ev.w, acc[4][3]);
    acc[5][0] = fmaf(sb.y, ev.x, acc[5][0]);
    acc[5][1] = fmaf(sb.y, ev.y, acc[5][1]);
    acc[5][2] = fmaf(sb.y, ev.z, acc[5][2]);
    acc[5][3] = fmaf(sb.y, ev.w, acc[5][3]);
    acc[6][0] = fmaf(sb.z, ev.x, acc[6][0]);
    acc[6][1] = fmaf(sb.z, ev.y, acc[6][1]);
    acc[6][2] = fmaf(sb.z, ev.z, acc[6][2]);
    acc[6][3] = fmaf(sb.z, ev.w, acc[6][3]);
    acc[7][0] = fmaf(sb.w, ev.x, acc[7][0]);
    acc[7][1] = fmaf(sb.w, ev.y, acc[7][1]);
    acc[7][2] = fmaf(sb.w, ev.z, acc[7][2]);
    acc[7][3] = fmaf(sb.w, ev.w, acc[7][3]);
  }
#pragma unroll
  for (int g = 0; g < 8; ++g) {
    float4 o;
    o.x = fmaxf(acc[g][0], 0.0f) * invT;
    o.y = fmaxf(acc[g][1], 0.0f) * invT;
    o.z = fmaxf(acc[g][2], 0.0f) * invT;
    o.w = fmaxf(acc[g][3], 0.0f) * invT;
    ((float4*)(&lgA[g][0]))[t] = o;
  }
  __syncthreads();

  // ---- phase B: selection; wave w handles rows 2w, 2w+1; lane l owns cols l+64j ----
  const int w = t >> 6, l = t & 63;

#pragma unroll 1
  for (int gi = 0; gi < 2; ++gi) {
    const int g = w * 2 + gi;
    float q[16];
#pragma unroll
    for (int j = 0; j < 16; ++j) q[j] = lgA[g][l + (j << 6)];

    float lm = q[0];
#pragma unroll
    for (int j = 1; j < 16; ++j) lm = fmaxf(lm, q[j]);
    const float qmax = wmaxf(lm);

    // bit-bisection for the 16th largest (q >= 0 so float bits are uint-ordered)
    u32 lo = 0u, hi = __float_as_uint(qmax) + 1u;
    u32 kept = 0u;
    bool f16 = false;
    float pvf = 0.0f;
#pragma unroll 1
    while (hi - lo > 1u) {
      u32 mid = (lo + hi) >> 1;
      float pv = __uint_as_float(mid);
      int cl = 0;
#pragma unroll
      for (int j = 0; j < 16; ++j) cl += (q[j] >= pv) ? 1 : 0;
      int cw = wsumi(cl);
      if (cw >= 16) lo = mid; else hi = mid;
      if (cw == 16) { f16 = true; pvf = pv; break; }
    }
    float theta, ub;
    if (f16) {
      float vmin = POSINF, umax = -1.0f;
#pragma unroll
      for (int j = 0; j < 16; ++j) {
        if (q[j] >= pvf) { kept |= 1u << j; vmin = fminf(vmin, q[j]); }
        else umax = fmaxf(umax, q[j]);
      }
      theta = wminf(vmin);   // 16th value
      ub = wmaxf(umax);      // 17th value
    } else {
      // exact ties at the fp32 16th value
      theta = __uint_as_float(lo);
      int cg = 0;
#pragma unroll
      for (int j = 0; j < 16; ++j)
        if (q[j] > theta) { kept |= 1u << j; cg++; }
      int cw = wsumi(cg);
      int r = 16 - cw;
#pragma unroll 1
      for (int it = 0; it < r; ++it) {
        u32 mc = 0xFFFFFFFFu;
#pragma unroll
        for (int j = 0; j < 16; ++j)
          if (q[j] == theta && !((kept >> j) & 1u)) {
            u32 cc = (u32)((j << 6) | l);
            mc = cc < mc ? cc : mc;
          }
        u32 wm = wminu(mc);
        if ((wm & 63u) == (u32)l) kept |= 1u << (wm >> 6);
      }
      ub = theta;  // gap 0 -> rescore
    }

    if (theta - ub >= MARG) {
      // ---- common path: boundary unambiguous at fp32 precision ----
      float e[16];
      float es = 0.0f, ek = 0.0f;
#pragma unroll
      for (int j = 0; j < 16; ++j) {
        e[j] = __expf(q[j] - qmax);
        es += e[j];
        if ((kept >> j) & 1u) ek += e[j];
      }
      const float Z = wsumf(es);
      const float EK = wsumf(ek);
      const float inv = 1.0f / (EK + 1e-8f * Z);
#pragma unroll
      for (int j = 0; j < 16; ++j)
        lgA[g][l + (j << 6)] = ((kept >> j) & 1u) ? (e[j] * inv) : 0.0f;
    } else {
      // ---- rescore path (rare): fp64 for boundary-adjacent cols ----
      double qd[16];
      const float thr = ub - MARG;
#pragma unroll 1
      for (int j = 0; j < 16; ++j) {
        if (q[j] >= thr) {
          const int m = l + (j << 6);
          const float* col = e2t + (size_t)m * 64;
          double a = 0.0;
          for (int d = 0; d < 64; ++d) {
            double s = (MODE == 0) ? (double)e1f[(erow + g) * 64 + d]
                                   : embD[(erow + g) * 64 + d];
            a = fma(s, (double)col[d], a);
          }
          qd[j] = (a > 0.0 ? a : 0.0) / Td;
        } else {
          qd[j] = (double)q[j];   // > MARG below boundary: can never enter top-16
        }
      }
      // round-5 exact fp64 selection (Dekker-pair wave reductions)
      double bm = qd[0];
#pragma unroll
      for (int j = 1; j < 16; ++j) bm = qd[j] > bm ? qd[j] : bm;
      float mh = (float)bm;
      float mlo = (float)(bm - (double)mh);
      float whi = wmaxf(mh);
      float wlo = wmaxf(mh == whi ? mlo : NEGINF);
      const double qmaxd = (double)whi + (double)wlo;

      float ev2[16];
      float es2 = 0.0f;
#pragma unroll
      for (int j = 0; j < 16; ++j) { ev2[j] = __expf((float)(qd[j] - qmaxd)); es2 += ev2[j]; }
      const float Z2 = wsumf(es2);

      u32 kept2 = 0;
      float EK2 = 0.0f;
#pragma unroll 1
      for (int it = 0; it < 16; ++it) {
        double bv = -1.0;
        int bjj = -1;
#pragma unroll
        for (int j = 0; j < 16; ++j) {
          bool tk = (((kept2 >> j) & 1u) == 0u) && (qd[j] > bv);
          bv = tk ? qd[j] : bv;
          bjj = tk ? j : bjj;
        }
        float bh = NEGINF, bl = NEGINF;
        if (bjj >= 0) { bh = (float)bv; bl = (float)(bv - (double)bh); }
        float vhi = wmaxf(bh);
        float vlo = wmaxf(bh == vhi ? bl : NEGINF);
        bool elig = (bh == vhi) && (bl == vlo);
        u32 mc = elig ? (u32)((bjj << 6) | l) : 0xFFFFFFFFu;
        u32 mwin = wminu(mc);
        EK2 += __expf((float)(((double)vhi + (double)vlo) - qmaxd));
        if ((mwin & 63u) == (u32)l) kept2 |= 1u << (mwin >> 6);
      }
      const float inv2 = 1.0f / (EK2 + 1e-8f * Z2);
#pragma unroll
      for (int j = 0; j < 16; ++j)
        lgA[g][l + (j << 6)] = ((kept2 >> j) & 1u) ? (ev2[j] * inv2) : 0.0f;
    }
  }
  __syncthreads();

  // ---- coalesced flush: 8 rows x 1024 fp32 ----
  float4* gout = (float4*)(outp + (size_t)r0 * 1024);
  const float4* src = (const float4*)(&lgA[0][0]);
#pragma unroll
  for (int k = 0; k < 8; ++k) {
    int i = t + k * 256;
    gout[i] = src[i];
  }
}

// ---------- kernel 4: fuse + edge MLP + head mean + sigmoid (fp32 io) ----------
__global__ __launch_bounds__(256) void k_fuse(const float* __restrict__ dyn,
                                              const float* __restrict__ stat,
                                              float* __restrict__ fin,
                                              const float* __restrict__ eW1,
                                              const float* __restrict__ eb1,
                                              const float* __restrict__ eW2,
                                              const float* __restrict__ eb2,
                                              const float* __restrict__ fwp) {
  const float w = fwp[0];
  const float w1 = 1.0f - w;
  float W1[4][8], B1v[8], W2v[8];
#pragma unroll
  for (int hh = 0; hh < 4; ++hh)
#pragma unroll
    for (int j = 0; j < 8; ++j) W1[hh][j] = eW1[hh * 8 + j];
#pragma unroll
  for (int j = 0; j < 8; ++j) { B1v[j] = eb1[j]; W2v[j] = eW2[j]; }
  const float b2 = eb2[0];

  const int i = blockIdx.x * 256 + threadIdx.x;   // [0, 4194304) float4s
  const int b = i >> 18;
  const int rem = i & 262143;
  const int n = rem >> 8;
  const int c4 = rem & 255;

  float fx[4][4];
#pragma unroll
  for (int hh = 0; hh < 4; ++hh) {
    float4 fd = ((const float4*)dyn)[(((size_t)((b * 4 + hh) * 1024 + n)) << 8) + c4];
    float4 fs = ((const float4*)stat)[(((size_t)(hh * 1024 + n)) << 8) + c4];
    fx[hh][0] = w1 * fs.x + w * fd.x;
    fx[hh][1] = w1 * fs.y + w * fd.y;
    fx[hh][2] = w1 * fs.z + w * fd.z;
    fx[hh][3] = w1 * fs.w + w * fd.w;
  }
  float ov[4];
#pragma unroll
  for (int x = 0; x < 4; ++x) {
    float ew = b2;
#pragma unroll
    for (int j = 0; j < 8; ++j) {
      float hj = B1v[j];
#pragma unroll
      for (int hh = 0; hh < 4; ++hh) hj = fmaf(fx[hh][x], W1[hh][j], hj);
      ew = fmaf(fmaxf(hj, 0.0f), W2v[j], ew);
    }
    float mean = (fx[0][x] + fx[1][x] + fx[2][x] + fx[3][x]) * 0.25f;
    float sg = 1.0f / (1.0f + __expf(-ew));
    ov[x] = sg * mean;
  }
  float4 o;
  o.x = ov[0]; o.y = ov[1]; o.z = ov[2]; o.w = ov[3];
  ((float4*)fin)[i] = o;
}

// ---------- launch ----------
extern "C" void kernel_launch(void* const* d_in, const int* in_sizes, int n_in,
                              void* d_out, int out_size, void* d_ws, size_t ws_size,
                              hipStream_t stream) {
  const float* pf   = (const float*)d_in[0];
  const float* E1   = (const float*)d_in[1];
  const float* E2   = (const float*)d_in[2];
  const float* temp = (const float*)d_in[3];
  const float* fw   = (const float*)d_in[4];
  const float* dW1  = (const float*)d_in[5];
  const float* db1  = (const float*)d_in[6];
  const float* ln_g = (const float*)d_in[7];
  const float* ln_b = (const float*)d_in[8];
  const float* dW2  = (const float*)d_in[9];
  const float* db2  = (const float*)d_in[10];
  const float* eW1  = (const float*)d_in[11];
  const float* eb1  = (const float*)d_in[12];
  const float* eW2  = (const float*)d_in[13];
  const float* eb2  = (const float*)d_in[14];

  // outputs are fp32, concatenated flat
  float* out_final = (float*)d_out;                              // 16,777,216 f
  float* out_stat  = out_final + (size_t)Bn * Nn * Nn;           // + 4,194,304 f
  float* out_dyn   = out_stat + (size_t)4 * Nn * Nn;             // +67,108,864 f

  // scratch inside final region (k_fuse, launched last, overwrites it):
  double* embD = (double*)d_out;                 // floats [0 .. 2,097,152)
  float* embF = out_final + 2097152;             // floats [2,097,152 .. 3,145,728)
  float* E2T  = out_final + 3145728;             // floats [3,145,728 .. 3,407,872)

  k_e2t<<<128, 256, 0, stream>>>(E2, E2T);
  k_meanmlp<<<Bn * Nn, 128, 0, stream>>>(pf, dW1, db1, ln_g, ln_b, dW2, db2, embD, embF);
  k_rows<0><<<512, 256, 0, stream>>>(E1, nullptr, nullptr, E2, E2T, temp, out_stat);
  k_rows<1><<<8192, 256, 0, stream>>>(nullptr, embD, embF, E2, E2T, temp, out_dyn);
  k_fuse<<<16384, 256, 0, stream>>>(out_dyn, out_stat, out_final, eW1, eb1, eW2, eb2, fw);
}

// Round 7
// 662.785 us; speedup vs baseline: 1.5294x; 1.0588x over previous
//
#include <hip/hip_runtime.h>

typedef unsigned int u32;
typedef unsigned long long u64;
typedef unsigned short u16;

#define Bn 16
#define Nn 1024
#define Pp 72
#define MARG 3e-4f

#define NEGINF __int_as_float(0xff800000)
#define POSINF __int_as_float(0x7f800000)

// ---------- wave helpers ----------
__device__ __forceinline__ float wsumf(float v) {
#pragma unroll
  for (int off = 1; off < 64; off <<= 1) v += __shfl_xor(v, off, 64);
  return v;
}
__device__ __forceinline__ float wmaxf(float v) {
#pragma unroll
  for (int off = 1; off < 64; off <<= 1) v = fmaxf(v, __shfl_xor(v, off, 64));
  return v;
}
__device__ __forceinline__ float wminf(float v) {
#pragma unroll
  for (int off = 1; off < 64; off <<= 1) v = fminf(v, __shfl_xor(v, off, 64));
  return v;
}
__device__ __forceinline__ u32 wminu(u32 v) {
#pragma unroll
  for (int off = 1; off < 64; off <<= 1) {
    u32 o = (u32)__shfl_xor((int)v, off, 64);
    v = (o < v) ? o : v;
  }
  return v;
}

// ---------- kernel 0: E2 transpose (per head): E2T[h][m][d] = E2[h][d][m] ----------
__global__ __launch_bounds__(256) void k_e2t(const float* __restrict__ E2,
                                             float* __restrict__ E2T) {
  __shared__ float tile[32][65];
  const int h = blockIdx.x >> 5;
  const int m0 = (blockIdx.x & 31) << 5;
  const float* src = E2 + (size_t)h * 65536;
  float* dst = E2T + (size_t)h * 65536;
  const int t = threadIdx.x;
#pragma unroll
  for (int k = 0; k < 8; ++k) {
    int idx = k * 256 + t;
    int d = idx >> 5, mm = idx & 31;
    tile[mm][d] = src[d * 1024 + m0 + mm];
  }
  __syncthreads();
#pragma unroll
  for (int k = 0; k < 8; ++k) {
    int idx = k * 256 + t;
    int mm = idx >> 6, d = idx & 63;
    dst[(size_t)(m0 + mm) * 64 + d] = tile[mm][d];
  }
}

// ---------- kernel 1: fused mean-over-P + node MLP (fp64), emits fp64+fp32 ----------
__global__ __launch_bounds__(128) void k_meanmlp(const float* __restrict__ pf,
                                                 const float* __restrict__ dW1,
                                                 const float* __restrict__ db1,
                                                 const float* __restrict__ ln_g,
                                                 const float* __restrict__ ln_b,
                                                 const float* __restrict__ dW2,
                                                 const float* __restrict__ db2,
                                                 double* __restrict__ embD,
                                                 float* __restrict__ embF) {
  __shared__ double ndD[96];
  __shared__ double red[64];
  __shared__ double h1r[64];
  const int t = threadIdx.x;
  const int bn = blockIdx.x;

  if (t < 96) {
    const float* src = pf + (size_t)bn * (Pp * 96) + t;
    double s = 0.0;
    for (int p = 0; p < Pp; ++p) s += (double)src[p * 96];
    ndD[t] = s / 72.0;
  }
  __syncthreads();

  double a = 0.0;
  if (t < 64) {
    a = (double)db1[t];
    for (int d = 0; d < 96; ++d) a = fma(ndD[d], (double)dW1[d * 64 + t], a);
    red[t] = a;
  }
  __syncthreads();
  for (int s2 = 32; s2 >= 1; s2 >>= 1) {
    if (t < s2) red[t] += red[t + s2];
    __syncthreads();
  }
  const double mu = red[0] * (1.0 / 64.0);
  __syncthreads();
  const double dv = a - mu;
  if (t < 64) red[t] = dv * dv;
  __syncthreads();
  for (int s2 = 32; s2 >= 1; s2 >>= 1) {
    if (t < s2) red[t] += red[t + s2];
    __syncthreads();
  }
  const double var = red[0] * (1.0 / 64.0);
  if (t < 64) {
    double xn = dv / sqrt(var + 1e-5) * (double)ln_g[t] + (double)ln_b[t];
    h1r[t] = xn > 0.0 ? xn : 0.0;
  }
  __syncthreads();
  if (t < 64) {
    double e = (double)db2[t];
    for (int k = 0; k < 64; ++k) e = fma(h1r[k], (double)dW2[k * 64 + t], e);
    embD[(size_t)bn * 64 + t] = e;
    embF[(size_t)bn * 64 + t] = (float)e;
  }
}

// ---------- kernel 2/3: graph rows ----------
// fp32 dot -> ballot-bisection top-16 -> (rare) fp64 boundary rescore -> renorm
// MODE 0: static (E1). MODE 1: dynamic (embF/embD).
template <int MODE>
__global__ __launch_bounds__(256) void k_rows(const float* __restrict__ e1f,
                                              const double* __restrict__ embD,
                                              const float* __restrict__ embF,
                                              const float* __restrict__ E2,
                                              const float* __restrict__ E2T,
                                              const float* __restrict__ temp,
                                              float* __restrict__ outp) {
  __shared__ float lgA[8][1024];   // fp32 logits, then fp32 output values
  __shared__ float embsh[64][8];   // emb staged [d][g]
  const int t = threadIdx.x;
  const int r0 = blockIdx.x * 8;   // 8 rows per block, same head
  int h;
  size_t erow;
  if (MODE == 0) {
    h = r0 >> 10;
    erow = (size_t)r0;
  } else {
    int b = r0 >> 12;
    h = (r0 >> 10) & 3;
    int n0 = r0 & 1023;
    erow = (size_t)(b << 10) + n0;
  }
  const float* efa = (MODE == 0) ? (e1f + erow * 64) : (embF + erow * 64);
  const float4* e2 = (const float4*)(E2 + (size_t)h * 65536);
  const float* e2t = E2T + (size_t)h * 65536;
  const float invT = 1.0f / temp[h];   // ranking-monotone; T=0.5 exact
  const double Td = (double)temp[h];

  // stage emb fp32 into LDS (transposed [d][g])
  for (int k = t; k < 512; k += 256) {
    int g = k & 7, d = k >> 3;
    embsh[d][g] = efa[g * 64 + d];
  }
  __syncthreads();

  // ---- phase A: fp32 dot; thread t owns cols 4t..4t+3 for all 8 rows ----
  float acc[8][4];
#pragma unroll
  for (int g = 0; g < 8; ++g)
#pragma unroll
    for (int x = 0; x < 4; ++x) acc[g][x] = 0.0f;

#pragma unroll 2
  for (int d = 0; d < 64; ++d) {
    float4 ev = e2[d * 256 + t];
    float4 sa = *(const float4*)&embsh[d][0];
    float4 sb = *(const float4*)&embsh[d][4];
    acc[0][0] = fmaf(sa.x, ev.x, acc[0][0]);
    acc[0][1] = fmaf(sa.x, ev.y, acc[0][1]);
    acc[0][2] = fmaf(sa.x, ev.z, acc[0][2]);
    acc[0][3] = fmaf(sa.x, ev.w, acc[0][3]);
    acc[1][0] = fmaf(sa.y, ev.x, acc[1][0]);
    acc[1][1] = fmaf(sa.y, ev.y, acc[1][1]);
    acc[1][2] = fmaf(sa.y, ev.z, acc[1][2]);
    acc[1][3] = fmaf(sa.y, ev.w, acc[1][3]);
    acc[2][0] = fmaf(sa.z, ev.x, acc[2][0]);
    acc[2][1] = fmaf(sa.z, ev.y, acc[2][1]);
    acc[2][2] = fmaf(sa.z, ev.z, acc[2][2]);
    acc[2][3] = fmaf(sa.z, ev.w, acc[2][3]);
    acc[3][0] = fmaf(sa.w, ev.x, acc[3][0]);
    acc[3][1] = fmaf(sa.w, ev.y, acc[3][1]);
    acc[3][2] = fmaf(sa.w, ev.z, acc[3][2]);
    acc[3][3] = fmaf(sa.w, ev.w, acc[3][3]);
    acc[4][0] = fmaf(sb.x, ev.x, acc[4][0]);
    acc[4][1] = fmaf(sb.x, ev.y, acc[4][1]);
    acc[4][2] = fmaf(sb.x, ev.z, acc[4][2]);
    acc[4][3] = fmaf(sb.x, ev.w, acc[4][3]);
    acc[5][0] = fmaf(sb.y, ev.x, acc[5][0]);
    acc[5][1] = fmaf(sb.y, ev.y, acc[5][1]);
    acc[5][2] = fmaf(sb.y, ev.z, acc[5][2]);
    acc[5][3] = fmaf(sb.y, ev.w, acc[5][3]);
    acc[6][0] = fmaf(sb.z, ev.x, acc[6][0]);
    acc[6][1] = fmaf(sb.z, ev.y, acc[6][1]);
    acc[6][2] = fmaf(sb.z, ev.z, acc[6][2]);
    acc[6][3] = fmaf(sb.z, ev.w, acc[6][3]);
    acc[7][0] = fmaf(sb.w, ev.x, acc[7][0]);
    acc[7][1] = fmaf(sb.w, ev.y, acc[7][1]);
    acc[7][2] = fmaf(sb.w, ev.z, acc[7][2]);
    acc[7][3] = fmaf(sb.w, ev.w, acc[7][3]);
  }
#pragma unroll
  for (int g = 0; g < 8; ++g) {
    float4 o;
    o.x = fmaxf(acc[g][0], 0.0f) * invT;
    o.y = fmaxf(acc[g][1], 0.0f) * invT;
    o.z = fmaxf(acc[g][2], 0.0f) * invT;
    o.w = fmaxf(acc[g][3], 0.0f) * invT;
    ((float4*)(&lgA[g][0]))[t] = o;
  }
  __syncthreads();

  // ---- phase B: selection; wave w handles rows 2w, 2w+1; lane l owns cols l+64j ----
  const int w = t >> 6, l = t & 63;

#pragma unroll 1
  for (int gi = 0; gi < 2; ++gi) {
    const int g = w * 2 + gi;
    float q[16];
#pragma unroll
    for (int j = 0; j < 16; ++j) q[j] = lgA[g][l + (j << 6)];

    float lm = q[0];
#pragma unroll
    for (int j = 1; j < 16; ++j) lm = fmaxf(lm, q[j]);
    const float qmax = wmaxf(lm);

    // bit-bisection for the 16th largest (q >= 0 so float bits are uint-ordered)
    // count via ballot+popc (no cross-lane latency chain)
    u32 lo = 0u, hi = __float_as_uint(qmax) + 1u;
    u32 kept = 0u;
    bool f16 = false;
    float pvf = 0.0f;
#pragma unroll 1
    while (hi - lo > 1u) {
      u32 mid = (lo + hi) >> 1;
      float pv = __uint_as_float(mid);
      u32 cw = 0;
#pragma unroll
      for (int j = 0; j < 16; ++j)
        cw += (u32)__popcll(__ballot(q[j] >= pv));
      if (cw >= 16u) lo = mid; else hi = mid;
      if (cw == 16u) { f16 = true; pvf = pv; break; }
    }
    float theta, ub;
    if (f16) {
      float vmin = POSINF, umax = -1.0f;
#pragma unroll
      for (int j = 0; j < 16; ++j) {
        if (q[j] >= pvf) { kept |= 1u << j; vmin = fminf(vmin, q[j]); }
        else umax = fmaxf(umax, q[j]);
      }
      theta = wminf(vmin);   // 16th value
      ub = wmaxf(umax);      // 17th value
    } else {
      // exact ties at the fp32 16th value
      theta = __uint_as_float(lo);
      u32 cw = 0;
#pragma unroll
      for (int j = 0; j < 16; ++j) {
        u64 bj = __ballot(q[j] > theta);
        cw += (u32)__popcll(bj);
        if (q[j] > theta) kept |= 1u << j;
      }
      int r = 16 - (int)cw;
#pragma unroll 1
      for (int it = 0; it < r; ++it) {
        u32 mc = 0xFFFFFFFFu;
#pragma unroll
        for (int j = 0; j < 16; ++j)
          if (q[j] == theta && !((kept >> j) & 1u)) {
            u32 cc = (u32)((j << 6) | l);
            mc = cc < mc ? cc : mc;
          }
        u32 wm = wminu(mc);
        if ((wm & 63u) == (u32)l) kept |= 1u << (wm >> 6);
      }
      ub = theta;  // gap 0 -> rescore
    }

    if (theta - ub >= MARG) {
      // ---- common path: boundary unambiguous at fp32 precision ----
      float e[16];
      float es = 0.0f, ek = 0.0f;
#pragma unroll
      for (int j = 0; j < 16; ++j) {
        e[j] = __expf(q[j] - qmax);
        es += e[j];
        if ((kept >> j) & 1u) ek += e[j];
      }
      const float Z = wsumf(es);
      const float EK = wsumf(ek);
      const float inv = 1.0f / (EK + 1e-8f * Z);
#pragma unroll
      for (int j = 0; j < 16; ++j)
        lgA[g][l + (j << 6)] = ((kept >> j) & 1u) ? (e[j] * inv) : 0.0f;
    } else {
      // ---- rescore path (rare): fp64 for boundary-adjacent cols ----
      double qd[16];
      const float thr = ub - MARG;
#pragma unroll 1
      for (int j = 0; j < 16; ++j) {
        if (q[j] >= thr) {
          const int m = l + (j << 6);
          const float* col = e2t + (size_t)m * 64;
          double a = 0.0;
          for (int d = 0; d < 64; ++d) {
            double s = (MODE == 0) ? (double)e1f[(erow + g) * 64 + d]
                                   : embD[(erow + g) * 64 + d];
            a = fma(s, (double)col[d], a);
          }
          qd[j] = (a > 0.0 ? a : 0.0) / Td;
        } else {
          qd[j] = (double)q[j];   // > MARG below boundary: can never enter top-16
        }
      }
      // exact fp64 selection (Dekker-pair wave reductions)
      double bm = qd[0];
#pragma unroll
      for (int j = 1; j < 16; ++j) bm = qd[j] > bm ? qd[j] : bm;
      float mh = (float)bm;
      float mlo = (float)(bm - (double)mh);
      float whi = wmaxf(mh);
      float wlo = wmaxf(mh == whi ? mlo : NEGINF);
      const double qmaxd = (double)whi + (double)wlo;

      float ev2[16];
      float es2 = 0.0f;
#pragma unroll
      for (int j = 0; j < 16; ++j) { ev2[j] = __expf((float)(qd[j] - qmaxd)); es2 += ev2[j]; }
      const float Z2 = wsumf(es2);

      u32 kept2 = 0;
      float EK2 = 0.0f;
#pragma unroll 1
      for (int it = 0; it < 16; ++it) {
        double bv = -1.0;
        int bjj = -1;
#pragma unroll
        for (int j = 0; j < 16; ++j) {
          bool tk = (((kept2 >> j) & 1u) == 0u) && (qd[j] > bv);
          bv = tk ? qd[j] : bv;
          bjj = tk ? j : bjj;
        }
        float bh = NEGINF, bl = NEGINF;
        if (bjj >= 0) { bh = (float)bv; bl = (float)(bv - (double)bh); }
        float vhi = wmaxf(bh);
        float vlo = wmaxf(bh == vhi ? bl : NEGINF);
        bool elig = (bh == vhi) && (bl == vlo);
        u32 mc = elig ? (u32)((bjj << 6) | l) : 0xFFFFFFFFu;
        u32 mwin = wminu(mc);
        EK2 += __expf((float)(((double)vhi + (double)vlo) - qmaxd));
        if ((mwin & 63u) == (u32)l) kept2 |= 1u << (mwin >> 6);
      }
      const float inv2 = 1.0f / (EK2 + 1e-8f * Z2);
#pragma unroll
      for (int j = 0; j < 16; ++j)
        lgA[g][l + (j << 6)] = ((kept2 >> j) & 1u) ? (ev2[j] * inv2) : 0.0f;
    }
  }
  __syncthreads();

  // ---- coalesced flush: 8 rows x 1024 fp32 ----
  float4* gout = (float4*)(outp + (size_t)r0 * 1024);
  const float4* src = (const float4*)(&lgA[0][0]);
#pragma unroll
  for (int k = 0; k < 8; ++k) {
    int i = t + k * 256;
    gout[i] = src[i];
  }
}

// ---------- kernel 4: fuse + edge MLP + head mean + sigmoid (fp32 io) ----------
__global__ __launch_bounds__(256) void k_fuse(const float* __restrict__ dyn,
                                              const float* __restrict__ stat,
                                              float* __restrict__ fin,
                                              const float* __restrict__ eW1,
                                              const float* __restrict__ eb1,
                                              const float* __restrict__ eW2,
                                              const float* __restrict__ eb2,
                                              const float* __restrict__ fwp) {
  const float w = fwp[0];
  const float w1 = 1.0f - w;
  float W1[4][8], B1v[8], W2v[8];
#pragma unroll
  for (int hh = 0; hh < 4; ++hh)
#pragma unroll
    for (int j = 0; j < 8; ++j) W1[hh][j] = eW1[hh * 8 + j];
#pragma unroll
  for (int j = 0; j < 8; ++j) { B1v[j] = eb1[j]; W2v[j] = eW2[j]; }
  const float b2 = eb2[0];

  const int i = blockIdx.x * 256 + threadIdx.x;   // [0, 4194304) float4s
  const int b = i >> 18;
  const int rem = i & 262143;
  const int n = rem >> 8;
  const int c4 = rem & 255;

  float fx[4][4];
#pragma unroll
  for (int hh = 0; hh < 4; ++hh) {
    float4 fd = ((const float4*)dyn)[(((size_t)((b * 4 + hh) * 1024 + n)) << 8) + c4];
    float4 fs = ((const float4*)stat)[(((size_t)(hh * 1024 + n)) << 8) + c4];
    fx[hh][0] = w1 * fs.x + w * fd.x;
    fx[hh][1] = w1 * fs.y + w * fd.y;
    fx[hh][2] = w1 * fs.z + w * fd.z;
    fx[hh][3] = w1 * fs.w + w * fd.w;
  }
  float ov[4];
#pragma unroll
  for (int x = 0; x < 4; ++x) {
    float ew = b2;
#pragma unroll
    for (int j = 0; j < 8; ++j) {
      float hj = B1v[j];
#pragma unroll
      for (int hh = 0; hh < 4; ++hh) hj = fmaf(fx[hh][x], W1[hh][j], hj);
      ew = fmaf(fmaxf(hj, 0.0f), W2v[j], ew);
    }
    float mean = (fx[0][x] + fx[1][x] + fx[2][x] + fx[3][x]) * 0.25f;
    float sg = 1.0f / (1.0f + __expf(-ew));
    ov[x] = sg * mean;
  }
  float4 o;
  o.x = ov[0]; o.y = ov[1]; o.z = ov[2]; o.w = ov[3];
  ((float4*)fin)[i] = o;
}

// ---------- launch ----------
extern "C" void kernel_launch(void* const* d_in, const int* in_sizes, int n_in,
                              void* d_out, int out_size, void* d_ws, size_t ws_size,
                              hipStream_t stream) {
  const float* pf   = (const float*)d_in[0];
  const float* E1   = (const float*)d_in[1];
  const float* E2   = (const float*)d_in[2];
  const float* temp = (const float*)d_in[3];
  const float* fw   = (const float*)d_in[4];
  const float* dW1  = (const float*)d_in[5];
  const float* db1  = (const float*)d_in[6];
  const float* ln_g = (const float*)d_in[7];
  const float* ln_b = (const float*)d_in[8];
  const float* dW2  = (const float*)d_in[9];
  const float* db2  = (const float*)d_in[10];
  const float* eW1  = (const float*)d_in[11];
  const float* eb1  = (const float*)d_in[12];
  const float* eW2  = (const float*)d_in[13];
  const float* eb2  = (const float*)d_in[14];

  // outputs are fp32, concatenated flat
  float* out_final = (float*)d_out;                              // 16,777,216 f
  float* out_stat  = out_final + (size_t)Bn * Nn * Nn;           // + 4,194,304 f
  float* out_dyn   = out_stat + (size_t)4 * Nn * Nn;             // +67,108,864 f

  // scratch inside final region (k_fuse, launched last, overwrites it):
  double* embD = (double*)d_out;                 // floats [0 .. 2,097,152)
  float* embF = out_final + 2097152;             // floats [2,097,152 .. 3,145,728)
  float* E2T  = out_final + 3145728;             // floats [3,145,728 .. 3,407,872)

  k_e2t<<<128, 256, 0, stream>>>(E2, E2T);
  k_meanmlp<<<Bn * Nn, 128, 0, stream>>>(pf, dW1, db1, ln_g, ln_b, dW2, db2, embD, embF);
  k_rows<0><<<512, 256, 0, stream>>>(E1, nullptr, nullptr, E2, E2T, temp, out_stat);
  k_rows<1><<<8192, 256, 0, stream>>>(nullptr, embD, embF, E2, E2T, temp, out_dyn);
  k_fuse<<<16384, 256, 0, stream>>>(out_dyn, out_stat, out_final, eW1, eb1, eW2, eb2, fw);
}

// Round 8
// 604.503 us; speedup vs baseline: 1.6769x; 1.0964x over previous
//
#include <hip/hip_runtime.h>

typedef unsigned int u32;
typedef unsigned long long u64;
typedef unsigned short u16;

#define Bn 16
#define Nn 1024
#define Pp 72
#define MARG 3e-4f

#define NEGINF __int_as_float(0xff800000)
#define POSINF __int_as_float(0x7f800000)

// ---------- DPP wave-64 reductions (VALU-only, ~6 dependent steps) ----------
// ladder: row_shr 1/2/4/8 (within 16-lane rows) -> row_bcast15 -> row_bcast31;
// full reduction lands in lane 63; broadcast via readlane. old=own-value makes
// masked/invalid lanes a no-op for max/min; for sum, lane 63's chain only ever
// consumes valid sources, so the same ladder is exact (only lane 63 is read).
#define DPP_STEP(OP, CTRL, RM)                                                 \
  y = __builtin_amdgcn_update_dpp(__float_as_int(v), __float_as_int(v),        \
                                  CTRL, RM, 0xf, false);                       \
  v = OP(v, __int_as_float(y));

#define DPP_RED(NAME, OP)                                                      \
  __device__ __forceinline__ float NAME(float v) {                             \
    int y;                                                                     \
    DPP_STEP(OP, 0x111, 0xf)                                                   \
    DPP_STEP(OP, 0x112, 0xf)                                                   \
    DPP_STEP(OP, 0x114, 0xf)                                                   \
    DPP_STEP(OP, 0x118, 0xf)                                                   \
    DPP_STEP(OP, 0x142, 0xa)                                                   \
    DPP_STEP(OP, 0x143, 0xc)                                                   \
    return __int_as_float(__builtin_amdgcn_readlane(__float_as_int(v), 63));   \
  }

#define FADDOP(a, b) ((a) + (b))
DPP_RED(dmaxf, fmaxf)
DPP_RED(dminf, fminf)
DPP_RED(dsumf, FADDOP)

// shuffle-based u32 min (rare tie path only)
__device__ __forceinline__ u32 wminu(u32 v) {
#pragma unroll
  for (int off = 1; off < 64; off <<= 1) {
    u32 o = (u32)__shfl_xor((int)v, off, 64);
    v = (o < v) ? o : v;
  }
  return v;
}

// ---------- kernel 0: E2 transpose (per head): E2T[h][m][d] = E2[h][d][m] ----------
__global__ __launch_bounds__(256) void k_e2t(const float* __restrict__ E2,
                                             float* __restrict__ E2T) {
  __shared__ float tile[32][65];
  const int h = blockIdx.x >> 5;
  const int m0 = (blockIdx.x & 31) << 5;
  const float* src = E2 + (size_t)h * 65536;
  float* dst = E2T + (size_t)h * 65536;
  const int t = threadIdx.x;
#pragma unroll
  for (int k = 0; k < 8; ++k) {
    int idx = k * 256 + t;
    int d = idx >> 5, mm = idx & 31;
    tile[mm][d] = src[d * 1024 + m0 + mm];
  }
  __syncthreads();
#pragma unroll
  for (int k = 0; k < 8; ++k) {
    int idx = k * 256 + t;
    int mm = idx >> 6, d = idx & 63;
    dst[(size_t)(m0 + mm) * 64 + d] = tile[mm][d];
  }
}

// ---------- kernel 1: fused mean-over-P + node MLP (fp64), emits fp64+fp32 ----------
__global__ __launch_bounds__(128) void k_meanmlp(const float* __restrict__ pf,
                                                 const float* __restrict__ dW1,
                                                 const float* __restrict__ db1,
                                                 const float* __restrict__ ln_g,
                                                 const float* __restrict__ ln_b,
                                                 const float* __restrict__ dW2,
                                                 const float* __restrict__ db2,
                                                 double* __restrict__ embD,
                                                 float* __restrict__ embF) {
  __shared__ double ndD[96];
  __shared__ double red[64];
  __shared__ double h1r[64];
  const int t = threadIdx.x;
  const int bn = blockIdx.x;

  if (t < 96) {
    const float* src = pf + (size_t)bn * (Pp * 96) + t;
    double s = 0.0;
    for (int p = 0; p < Pp; ++p) s += (double)src[p * 96];
    ndD[t] = s / 72.0;
  }
  __syncthreads();

  double a = 0.0;
  if (t < 64) {
    a = (double)db1[t];
    for (int d = 0; d < 96; ++d) a = fma(ndD[d], (double)dW1[d * 64 + t], a);
    red[t] = a;
  }
  __syncthreads();
  for (int s2 = 32; s2 >= 1; s2 >>= 1) {
    if (t < s2) red[t] += red[t + s2];
    __syncthreads();
  }
  const double mu = red[0] * (1.0 / 64.0);
  __syncthreads();
  const double dv = a - mu;
  if (t < 64) red[t] = dv * dv;
  __syncthreads();
  for (int s2 = 32; s2 >= 1; s2 >>= 1) {
    if (t < s2) red[t] += red[t + s2];
    __syncthreads();
  }
  const double var = red[0] * (1.0 / 64.0);
  if (t < 64) {
    double xn = dv / sqrt(var + 1e-5) * (double)ln_g[t] + (double)ln_b[t];
    h1r[t] = xn > 0.0 ? xn : 0.0;
  }
  __syncthreads();
  if (t < 64) {
    double e = (double)db2[t];
    for (int k = 0; k < 64; ++k) e = fma(h1r[k], (double)dW2[k * 64 + t], e);
    embD[(size_t)bn * 64 + t] = e;
    embF[(size_t)bn * 64 + t] = (float)e;
  }
}

// ---------- kernel 2/3: graph rows ----------
// 512 threads = 8 waves; 8 rows/block; selection = 1 row per wave.
// fp32 dot -> ballot-bisection top-16 -> (rare) fp64 boundary rescore -> renorm
template <int MODE>
__global__ __launch_bounds__(512) void k_rows(const float* __restrict__ e1f,
                                              const double* __restrict__ embD,
                                              const float* __restrict__ embF,
                                              const float* __restrict__ E2,
                                              const float* __restrict__ E2T,
                                              const float* __restrict__ temp,
                                              float* __restrict__ outp) {
  __shared__ float lgA[8][1024];   // fp32 logits, then fp32 output values
  __shared__ float embsh[64][8];   // emb staged [d][g]
  const int t = threadIdx.x;
  const int r0 = blockIdx.x * 8;   // 8 rows per block, same head
  int h;
  size_t erow;
  if (MODE == 0) {
    h = r0 >> 10;
    erow = (size_t)r0;
  } else {
    int b = r0 >> 12;
    h = (r0 >> 10) & 3;
    int n0 = r0 & 1023;
    erow = (size_t)(b << 10) + n0;
  }
  const float* efa = (MODE == 0) ? (e1f + erow * 64) : (embF + erow * 64);
  const float2* e2 = (const float2*)(E2 + (size_t)h * 65536);
  const float* e2t = E2T + (size_t)h * 65536;
  const float invT = 1.0f / temp[h];   // ranking-monotone; T=0.5 exact
  const double Td = (double)temp[h];

  // stage emb fp32 into LDS (transposed [d][g]); 512 elements, 1 per thread
  {
    int g = t & 7, d = t >> 3;
    embsh[d][g] = efa[g * 64 + d];
  }
  __syncthreads();

  // ---- phase A: fp32 dot; thread t owns cols 2t, 2t+1 for all 8 rows ----
  // per-column summation order (d ascending) identical to prior rounds.
  float acc[8][2];
#pragma unroll
  for (int g = 0; g < 8; ++g) { acc[g][0] = 0.0f; acc[g][1] = 0.0f; }

#pragma unroll 4
  for (int d = 0; d < 64; ++d) {
    float2 ev = e2[d * 512 + t];
    float4 sa = *(const float4*)&embsh[d][0];
    float4 sb = *(const float4*)&embsh[d][4];
    acc[0][0] = fmaf(sa.x, ev.x, acc[0][0]);
    acc[0][1] = fmaf(sa.x, ev.y, acc[0][1]);
    acc[1][0] = fmaf(sa.y, ev.x, acc[1][0]);
    acc[1][1] = fmaf(sa.y, ev.y, acc[1][1]);
    acc[2][0] = fmaf(sa.z, ev.x, acc[2][0]);
    acc[2][1] = fmaf(sa.z, ev.y, acc[2][1]);
    acc[3][0] = fmaf(sa.w, ev.x, acc[3][0]);
    acc[3][1] = fmaf(sa.w, ev.y, acc[3][1]);
    acc[4][0] = fmaf(sb.x, ev.x, acc[4][0]);
    acc[4][1] = fmaf(sb.x, ev.y, acc[4][1]);
    acc[5][0] = fmaf(sb.y, ev.x, acc[5][0]);
    acc[5][1] = fmaf(sb.y, ev.y, acc[5][1]);
    acc[6][0] = fmaf(sb.z, ev.x, acc[6][0]);
    acc[6][1] = fmaf(sb.z, ev.y, acc[6][1]);
    acc[7][0] = fmaf(sb.w, ev.x, acc[7][0]);
    acc[7][1] = fmaf(sb.w, ev.y, acc[7][1]);
  }
#pragma unroll
  for (int g = 0; g < 8; ++g) {
    float2 o;
    o.x = fmaxf(acc[g][0], 0.0f) * invT;
    o.y = fmaxf(acc[g][1], 0.0f) * invT;
    ((float2*)(&lgA[g][0]))[t] = o;
  }
  __syncthreads();

  // ---- phase B: selection; wave w handles row w; lane l owns cols l+64j ----
  const int w = t >> 6, l = t & 63;
  {
    const int g = w;
    float q[16];
#pragma unroll
    for (int j = 0; j < 16; ++j) q[j] = lgA[g][l + (j << 6)];

    float lm = q[0];
#pragma unroll
    for (int j = 1; j < 16; ++j) lm = fmaxf(lm, q[j]);
    const float qmax = dmaxf(lm);

    // bit-bisection for the 16th largest (q >= 0 so float bits are uint-ordered)
    u32 lo = 0u, hi = __float_as_uint(qmax) + 1u;
    u32 kept = 0u;
    bool f16 = false;
    float pvf = 0.0f;
#pragma unroll 1
    while (hi - lo > 1u) {
      u32 mid = (lo + hi) >> 1;
      float pv = __uint_as_float(mid);
      u32 cw = 0;
#pragma unroll
      for (int j = 0; j < 16; ++j)
        cw += (u32)__popcll(__ballot(q[j] >= pv));
      if (cw >= 16u) lo = mid; else hi = mid;
      if (cw == 16u) { f16 = true; pvf = pv; break; }
    }
    float theta, ub;
    if (f16) {
      float vmin = POSINF, umax = -1.0f;
#pragma unroll
      for (int j = 0; j < 16; ++j) {
        if (q[j] >= pvf) { kept |= 1u << j; vmin = fminf(vmin, q[j]); }
        else umax = fmaxf(umax, q[j]);
      }
      theta = dminf(vmin);   // 16th value
      ub = dmaxf(umax);      // 17th value
    } else {
      // exact ties at the fp32 16th value
      theta = __uint_as_float(lo);
      u32 cw = 0;
#pragma unroll
      for (int j = 0; j < 16; ++j) {
        cw += (u32)__popcll(__ballot(q[j] > theta));
        if (q[j] > theta) kept |= 1u << j;
      }
      int r = 16 - (int)cw;
#pragma unroll 1
      for (int it = 0; it < r; ++it) {
        u32 mc = 0xFFFFFFFFu;
#pragma unroll
        for (int j = 0; j < 16; ++j)
          if (q[j] == theta && !((kept >> j) & 1u)) {
            u32 cc = (u32)((j << 6) | l);
            mc = cc < mc ? cc : mc;
          }
        u32 wm = wminu(mc);
        if ((wm & 63u) == (u32)l) kept |= 1u << (wm >> 6);
      }
      ub = theta;  // gap 0 -> rescore
    }

    if (theta - ub >= MARG) {
      // ---- common path: boundary unambiguous at fp32 precision ----
      float e[16];
      float es = 0.0f, ek = 0.0f;
#pragma unroll
      for (int j = 0; j < 16; ++j) {
        e[j] = __expf(q[j] - qmax);
        es += e[j];
        if ((kept >> j) & 1u) ek += e[j];
      }
      const float Z = dsumf(es);
      const float EK = dsumf(ek);
      const float inv = 1.0f / (EK + 1e-8f * Z);
#pragma unroll
      for (int j = 0; j < 16; ++j)
        lgA[g][l + (j << 6)] = ((kept >> j) & 1u) ? (e[j] * inv) : 0.0f;
    } else {
      // ---- rescore path (rare): fp64 for boundary-adjacent cols ----
      double qd[16];
      const float thr = ub - MARG;
#pragma unroll 1
      for (int j = 0; j < 16; ++j) {
        if (q[j] >= thr) {
          const int m = l + (j << 6);
          const float* col = e2t + (size_t)m * 64;
          double a = 0.0;
          for (int d = 0; d < 64; ++d) {
            double s = (MODE == 0) ? (double)e1f[(erow + g) * 64 + d]
                                   : embD[(erow + g) * 64 + d];
            a = fma(s, (double)col[d], a);
          }
          qd[j] = (a > 0.0 ? a : 0.0) / Td;
        } else {
          qd[j] = (double)q[j];   // > MARG below boundary: can never enter top-16
        }
      }
      // exact fp64 selection (Dekker-pair reductions, DPP-based)
      double bm = qd[0];
#pragma unroll
      for (int j = 1; j < 16; ++j) bm = qd[j] > bm ? qd[j] : bm;
      float mh = (float)bm;
      float mlo = (float)(bm - (double)mh);
      float whi = dmaxf(mh);
      float wlo = dmaxf(mh == whi ? mlo : NEGINF);
      const double qmaxd = (double)whi + (double)wlo;

      float ev2[16];
      float es2 = 0.0f;
#pragma unroll
      for (int j = 0; j < 16; ++j) { ev2[j] = __expf((float)(qd[j] - qmaxd)); es2 += ev2[j]; }
      const float Z2 = dsumf(es2);

      u32 kept2 = 0;
      float EK2 = 0.0f;
#pragma unroll 1
      for (int it = 0; it < 16; ++it) {
        double bv = -1.0;
        int bjj = -1;
#pragma unroll
        for (int j = 0; j < 16; ++j) {
          bool tk = (((kept2 >> j) & 1u) == 0u) && (qd[j] > bv);
          bv = tk ? qd[j] : bv;
          bjj = tk ? j : bjj;
        }
        float bh = NEGINF, bl = NEGINF;
        if (bjj >= 0) { bh = (float)bv; bl = (float)(bv - (double)bh); }
        float vhi = dmaxf(bh);
        float vlo = dmaxf(bh == vhi ? bl : NEGINF);
        bool elig = (bh == vhi) && (bl == vlo);
        u32 mc = elig ? (u32)((bjj << 6) | l) : 0xFFFFFFFFu;
        u32 mwin = wminu(mc);
        EK2 += __expf((float)(((double)vhi + (double)vlo) - qmaxd));
        if ((mwin & 63u) == (u32)l) kept2 |= 1u << (mwin >> 6);
      }
      const float inv2 = 1.0f / (EK2 + 1e-8f * Z2);
#pragma unroll
      for (int j = 0; j < 16; ++j)
        lgA[g][l + (j << 6)] = ((kept2 >> j) & 1u) ? (ev2[j] * inv2) : 0.0f;
    }
  }
  __syncthreads();

  // ---- coalesced flush: 8 rows x 1024 fp32 = 2048 float4 by 512 threads ----
  float4* gout = (float4*)(outp + (size_t)r0 * 1024);
  const float4* src = (const float4*)(&lgA[0][0]);
#pragma unroll
  for (int k = 0; k < 4; ++k) {
    int i = t + k * 512;
    gout[i] = src[i];
  }
}

// ---------- kernel 4: fuse + edge MLP + head mean + sigmoid (fp32 io) ----------
__global__ __launch_bounds__(256) void k_fuse(const float* __restrict__ dyn,
                                              const float* __restrict__ stat,
                                              float* __restrict__ fin,
                                              const float* __restrict__ eW1,
                                              const float* __restrict__ eb1,
                                              const float* __restrict__ eW2,
                                              const float* __restrict__ eb2,
                                              const float* __restrict__ fwp) {
  const float w = fwp[0];
  const float w1 = 1.0f - w;
  float W1[4][8], B1v[8], W2v[8];
#pragma unroll
  for (int hh = 0; hh < 4; ++hh)
#pragma unroll
    for (int j = 0; j < 8; ++j) W1[hh][j] = eW1[hh * 8 + j];
#pragma unroll
  for (int j = 0; j < 8; ++j) { B1v[j] = eb1[j]; W2v[j] = eW2[j]; }
  const float b2 = eb2[0];

  const int i = blockIdx.x * 256 + threadIdx.x;   // [0, 4194304) float4s
  const int b = i >> 18;
  const int rem = i & 262143;
  const int n = rem >> 8;
  const int c4 = rem & 255;

  float fx[4][4];
#pragma unroll
  for (int hh = 0; hh < 4; ++hh) {
    float4 fd = ((const float4*)dyn)[(((size_t)((b * 4 + hh) * 1024 + n)) << 8) + c4];
    float4 fs = ((const float4*)stat)[(((size_t)(hh * 1024 + n)) << 8) + c4];
    fx[hh][0] = w1 * fs.x + w * fd.x;
    fx[hh][1] = w1 * fs.y + w * fd.y;
    fx[hh][2] = w1 * fs.z + w * fd.z;
    fx[hh][3] = w1 * fs.w + w * fd.w;
  }
  float ov[4];
#pragma unroll
  for (int x = 0; x < 4; ++x) {
    float ew = b2;
#pragma unroll
    for (int j = 0; j < 8; ++j) {
      float hj = B1v[j];
#pragma unroll
      for (int hh = 0; hh < 4; ++hh) hj = fmaf(fx[hh][x], W1[hh][j], hj);
      ew = fmaf(fmaxf(hj, 0.0f), W2v[j], ew);
    }
    float mean = (fx[0][x] + fx[1][x] + fx[2][x] + fx[3][x]) * 0.25f;
    float sg = 1.0f / (1.0f + __expf(-ew));
    ov[x] = sg * mean;
  }
  float4 o;
  o.x = ov[0]; o.y = ov[1]; o.z = ov[2]; o.w = ov[3];
  ((float4*)fin)[i] = o;
}

// ---------- launch ----------
extern "C" void kernel_launch(void* const* d_in, const int* in_sizes, int n_in,
                              void* d_out, int out_size, void* d_ws, size_t ws_size,
                              hipStream_t stream) {
  const float* pf   = (const float*)d_in[0];
  const float* E1   = (const float*)d_in[1];
  const float* E2   = (const float*)d_in[2];
  const float* temp = (const float*)d_in[3];
  const float* fw   = (const float*)d_in[4];
  const float* dW1  = (const float*)d_in[5];
  const float* db1  = (const float*)d_in[6];
  const float* ln_g = (const float*)d_in[7];
  const float* ln_b = (const float*)d_in[8];
  const float* dW2  = (const float*)d_in[9];
  const float* db2  = (const float*)d_in[10];
  const float* eW1  = (const float*)d_in[11];
  const float* eb1  = (const float*)d_in[12];
  const float* eW2  = (const float*)d_in[13];
  const float* eb2  = (const float*)d_in[14];

  // outputs are fp32, concatenated flat
  float* out_final = (float*)d_out;                              // 16,777,216 f
  float* out_stat  = out_final + (size_t)Bn * Nn * Nn;           // + 4,194,304 f
  float* out_dyn   = out_stat + (size_t)4 * Nn * Nn;             // +67,108,864 f

  // scratch inside final region (k_fuse, launched last, overwrites it):
  double* embD = (double*)d_out;                 // floats [0 .. 2,097,152)
  float* embF = out_final + 2097152;             // floats [2,097,152 .. 3,145,728)
  float* E2T  = out_final + 3145728;             // floats [3,145,728 .. 3,407,872)

  k_e2t<<<128, 256, 0, stream>>>(E2, E2T);
  k_meanmlp<<<Bn * Nn, 128, 0, stream>>>(pf, dW1, db1, ln_g, ln_b, dW2, db2, embD, embF);
  k_rows<0><<<512, 512, 0, stream>>>(E1, nullptr, nullptr, E2, E2T, temp, out_stat);
  k_rows<1><<<8192, 512, 0, stream>>>(nullptr, embD, embF, E2, E2T, temp, out_dyn);
  k_fuse<<<16384, 256, 0, stream>>>(out_dyn, out_stat, out_final, eW1, eb1, eW2, eb2, fw);
}

// Round 9
// 588.902 us; speedup vs baseline: 1.7213x; 1.0265x over previous
//
#include <hip/hip_runtime.h>

typedef unsigned int u32;
typedef unsigned long long u64;
typedef unsigned short u16;

#define Bn 16
#define Nn 1024
#define Pp 72
#define MARG 3e-4f

#define NEGINF __int_as_float(0xff800000)
#define POSINF __int_as_float(0x7f800000)

// ---------- DPP wave-64 reductions (VALU-only) ----------
#define DPP_STEP(OP, CTRL, RM)                                                 \
  y = __builtin_amdgcn_update_dpp(__float_as_int(v), __float_as_int(v),        \
                                  CTRL, RM, 0xf, false);                       \
  v = OP(v, __int_as_float(y));

#define DPP_RED(NAME, OP)                                                      \
  __device__ __forceinline__ float NAME(float v) {                             \
    int y;                                                                     \
    DPP_STEP(OP, 0x111, 0xf)                                                   \
    DPP_STEP(OP, 0x112, 0xf)                                                   \
    DPP_STEP(OP, 0x114, 0xf)                                                   \
    DPP_STEP(OP, 0x118, 0xf)                                                   \
    DPP_STEP(OP, 0x142, 0xa)                                                   \
    DPP_STEP(OP, 0x143, 0xc)                                                   \
    return __int_as_float(__builtin_amdgcn_readlane(__float_as_int(v), 63));   \
  }

#define FADDOP(a, b) ((a) + (b))
DPP_RED(dmaxf, fmaxf)
DPP_RED(dminf, fminf)
DPP_RED(dsumf, FADDOP)

__device__ __forceinline__ u32 wminu(u32 v) {
#pragma unroll
  for (int off = 1; off < 64; off <<= 1) {
    u32 o = (u32)__shfl_xor((int)v, off, 64);
    v = (o < v) ? o : v;
  }
  return v;
}

// ---------- kernel 0: E2 transpose (per head): E2T[h][m][d] = E2[h][d][m] ----------
__global__ __launch_bounds__(256) void k_e2t(const float* __restrict__ E2,
                                             float* __restrict__ E2T) {
  __shared__ float tile[32][65];
  const int h = blockIdx.x >> 5;
  const int m0 = (blockIdx.x & 31) << 5;
  const float* src = E2 + (size_t)h * 65536;
  float* dst = E2T + (size_t)h * 65536;
  const int t = threadIdx.x;
#pragma unroll
  for (int k = 0; k < 8; ++k) {
    int idx = k * 256 + t;
    int d = idx >> 5, mm = idx & 31;
    tile[mm][d] = src[d * 1024 + m0 + mm];
  }
  __syncthreads();
#pragma unroll
  for (int k = 0; k < 8; ++k) {
    int idx = k * 256 + t;
    int mm = idx >> 6, d = idx & 63;
    dst[(size_t)(m0 + mm) * 64 + d] = tile[mm][d];
  }
}

// ---------- kernel 1: fused mean-over-P + node MLP (fp64), emits fp64+fp32 ----------
__global__ __launch_bounds__(128) void k_meanmlp(const float* __restrict__ pf,
                                                 const float* __restrict__ dW1,
                                                 const float* __restrict__ db1,
                                                 const float* __restrict__ ln_g,
                                                 const float* __restrict__ ln_b,
                                                 const float* __restrict__ dW2,
                                                 const float* __restrict__ db2,
                                                 double* __restrict__ embD,
                                                 float* __restrict__ embF) {
  __shared__ double ndD[96];
  __shared__ double red[64];
  __shared__ double h1r[64];
  const int t = threadIdx.x;
  const int bn = blockIdx.x;

  if (t < 96) {
    const float* src = pf + (size_t)bn * (Pp * 96) + t;
    double s = 0.0;
    for (int p = 0; p < Pp; ++p) s += (double)src[p * 96];
    ndD[t] = s / 72.0;
  }
  __syncthreads();

  double a = 0.0;
  if (t < 64) {
    a = (double)db1[t];
    for (int d = 0; d < 96; ++d) a = fma(ndD[d], (double)dW1[d * 64 + t], a);
    red[t] = a;
  }
  __syncthreads();
  for (int s2 = 32; s2 >= 1; s2 >>= 1) {
    if (t < s2) red[t] += red[t + s2];
    __syncthreads();
  }
  const double mu = red[0] * (1.0 / 64.0);
  __syncthreads();
  const double dv = a - mu;
  if (t < 64) red[t] = dv * dv;
  __syncthreads();
  for (int s2 = 32; s2 >= 1; s2 >>= 1) {
    if (t < s2) red[t] += red[t + s2];
    __syncthreads();
  }
  const double var = red[0] * (1.0 / 64.0);
  if (t < 64) {
    double xn = dv / sqrt(var + 1e-5) * (double)ln_g[t] + (double)ln_b[t];
    h1r[t] = xn > 0.0 ? xn : 0.0;
  }
  __syncthreads();
  if (t < 64) {
    double e = (double)db2[t];
    for (int k = 0; k < 64; ++k) e = fma(h1r[k], (double)dW2[k * 64 + t], e);
    embD[(size_t)bn * 64 + t] = e;
    embF[(size_t)bn * 64 + t] = (float)e;
  }
}

// ---------- kernel 2a: DOT ONLY — 16 rows/block, logits straight to global ----------
// per-column fp32 fma order (d ascending) identical to prior rounds -> bit-identical.
template <int MODE>
__global__ __launch_bounds__(512) void k_dot(const float* __restrict__ e1f,
                                             const float* __restrict__ embF,
                                             const float* __restrict__ E2,
                                             const float* __restrict__ temp,
                                             float* __restrict__ outp) {
  __shared__ float embsh[64][16];
  const int t = threadIdx.x;
  const int r0 = blockIdx.x * 16;   // 16 rows per block, same head
  int h;
  size_t erow;
  if (MODE == 0) {
    h = r0 >> 10;
    erow = (size_t)r0;
  } else {
    int b = r0 >> 12;
    h = (r0 >> 10) & 3;
    int n0 = r0 & 1023;
    erow = (size_t)(b << 10) + n0;
  }
  const float* efa = (MODE == 0) ? (e1f + erow * 64) : (embF + erow * 64);
  const float2* e2 = (const float2*)(E2 + (size_t)h * 65536);
  const float invT = 1.0f / temp[h];

  // stage emb fp32 into LDS (transposed [d][g]); 1024 elems by 512 threads
#pragma unroll
  for (int i = t; i < 1024; i += 512) {
    int g = i & 15, d = i >> 4;
    embsh[d][g] = efa[g * 64 + d];
  }
  __syncthreads();

  float acc[16][2];
#pragma unroll
  for (int g = 0; g < 16; ++g) { acc[g][0] = 0.0f; acc[g][1] = 0.0f; }

#define FMA2(g, s)                                                             \
  acc[g][0] = fmaf(s, ev.x, acc[g][0]);                                        \
  acc[g][1] = fmaf(s, ev.y, acc[g][1]);

#pragma unroll 2
  for (int d = 0; d < 64; ++d) {
    float2 ev = e2[d * 512 + t];
    float4 sa = *(const float4*)&embsh[d][0];
    float4 sb = *(const float4*)&embsh[d][4];
    float4 sc = *(const float4*)&embsh[d][8];
    float4 sd = *(const float4*)&embsh[d][12];
    FMA2(0, sa.x) FMA2(1, sa.y) FMA2(2, sa.z) FMA2(3, sa.w)
    FMA2(4, sb.x) FMA2(5, sb.y) FMA2(6, sb.z) FMA2(7, sb.w)
    FMA2(8, sc.x) FMA2(9, sc.y) FMA2(10, sc.z) FMA2(11, sc.w)
    FMA2(12, sd.x) FMA2(13, sd.y) FMA2(14, sd.z) FMA2(15, sd.w)
  }
#undef FMA2

#pragma unroll
  for (int g = 0; g < 16; ++g) {
    float2 o;
    o.x = fmaxf(acc[g][0], 0.0f) * invT;
    o.y = fmaxf(acc[g][1], 0.0f) * invT;
    ((float2*)(outp + (size_t)(r0 + g) * 1024))[t] = o;
  }
}

// ---------- kernel 2b: SELECT — 1 row/wave, in-place sparsify, no LDS ----------
template <int MODE>
__global__ __launch_bounds__(256) void k_sel(const float* __restrict__ e1f,
                                             const double* __restrict__ embD,
                                             const float* __restrict__ E2T,
                                             const float* __restrict__ temp,
                                             float* __restrict__ outp) {
  const int t = threadIdx.x;
  const int w = t >> 6, l = t & 63;
  const int r = blockIdx.x * 4 + w;   // absolute row
  int h;
  size_t erow;
  if (MODE == 0) {
    h = r >> 10;
    erow = (size_t)r;
  } else {
    int b = r >> 12;
    h = (r >> 10) & 3;
    int n = r & 1023;
    erow = (size_t)(b << 10) + n;
  }
  const float* e2t = E2T + (size_t)h * 65536;
  const double Td = (double)temp[h];
  float* row = outp + (size_t)r * 1024;

  float q[16];
#pragma unroll
  for (int j = 0; j < 16; ++j) q[j] = row[l + (j << 6)];

  float lm = q[0];
#pragma unroll
  for (int j = 1; j < 16; ++j) lm = fmaxf(lm, q[j]);
  const float qmax = dmaxf(lm);

  // bit-bisection for the 16th largest (q >= 0 -> float bits uint-ordered)
  u32 lo = 0u, hi = __float_as_uint(qmax) + 1u;
  u32 kept = 0u;
  bool f16 = false;
  float pvf = 0.0f;
#pragma unroll 1
  while (hi - lo > 1u) {
    u32 mid = (lo + hi) >> 1;
    float pv = __uint_as_float(mid);
    u32 cw = 0;
#pragma unroll
    for (int j = 0; j < 16; ++j)
      cw += (u32)__popcll(__ballot(q[j] >= pv));
    if (cw >= 16u) lo = mid; else hi = mid;
    if (cw == 16u) { f16 = true; pvf = pv; break; }
  }
  float theta, ub;
  if (f16) {
    float vmin = POSINF, umax = -1.0f;
#pragma unroll
    for (int j = 0; j < 16; ++j) {
      if (q[j] >= pvf) { kept |= 1u << j; vmin = fminf(vmin, q[j]); }
      else umax = fmaxf(umax, q[j]);
    }
    theta = dminf(vmin);   // 16th value
    ub = dmaxf(umax);      // 17th value
  } else {
    theta = __uint_as_float(lo);
    u32 cw = 0;
#pragma unroll
    for (int j = 0; j < 16; ++j) {
      cw += (u32)__popcll(__ballot(q[j] > theta));
      if (q[j] > theta) kept |= 1u << j;
    }
    int rr = 16 - (int)cw;
#pragma unroll 1
    for (int it = 0; it < rr; ++it) {
      u32 mc = 0xFFFFFFFFu;
#pragma unroll
      for (int j = 0; j < 16; ++j)
        if (q[j] == theta && !((kept >> j) & 1u)) {
          u32 cc = (u32)((j << 6) | l);
          mc = cc < mc ? cc : mc;
        }
      u32 wm = wminu(mc);
      if ((wm & 63u) == (u32)l) kept |= 1u << (wm >> 6);
    }
    ub = theta;  // gap 0 -> rescore
  }

  if (theta - ub >= MARG) {
    float e[16];
    float es = 0.0f, ek = 0.0f;
#pragma unroll
    for (int j = 0; j < 16; ++j) {
      e[j] = __expf(q[j] - qmax);
      es += e[j];
      if ((kept >> j) & 1u) ek += e[j];
    }
    const float Z = dsumf(es);
    const float EK = dsumf(ek);
    const float inv = 1.0f / (EK + 1e-8f * Z);
#pragma unroll
    for (int j = 0; j < 16; ++j)
      row[l + (j << 6)] = ((kept >> j) & 1u) ? (e[j] * inv) : 0.0f;
  } else {
    // rescore path (rare): fp64 for boundary-adjacent cols
    double qd[16];
    const float thr = ub - MARG;
#pragma unroll 1
    for (int j = 0; j < 16; ++j) {
      if (q[j] >= thr) {
        const int m = l + (j << 6);
        const float* col = e2t + (size_t)m * 64;
        double a = 0.0;
        for (int d = 0; d < 64; ++d) {
          double s = (MODE == 0) ? (double)e1f[erow * 64 + d]
                                 : embD[erow * 64 + d];
          a = fma(s, (double)col[d], a);
        }
        qd[j] = (a > 0.0 ? a : 0.0) / Td;
      } else {
        qd[j] = (double)q[j];
      }
    }
    double bm = qd[0];
#pragma unroll
    for (int j = 1; j < 16; ++j) bm = qd[j] > bm ? qd[j] : bm;
    float mh = (float)bm;
    float mlo = (float)(bm - (double)mh);
    float whi = dmaxf(mh);
    float wlo = dmaxf(mh == whi ? mlo : NEGINF);
    const double qmaxd = (double)whi + (double)wlo;

    float ev2[16];
    float es2 = 0.0f;
#pragma unroll
    for (int j = 0; j < 16; ++j) { ev2[j] = __expf((float)(qd[j] - qmaxd)); es2 += ev2[j]; }
    const float Z2 = dsumf(es2);

    u32 kept2 = 0;
    float EK2 = 0.0f;
#pragma unroll 1
    for (int it = 0; it < 16; ++it) {
      double bv = -1.0;
      int bjj = -1;
#pragma unroll
      for (int j = 0; j < 16; ++j) {
        bool tk = (((kept2 >> j) & 1u) == 0u) && (qd[j] > bv);
        bv = tk ? qd[j] : bv;
        bjj = tk ? j : bjj;
      }
      float bh = NEGINF, bl = NEGINF;
      if (bjj >= 0) { bh = (float)bv; bl = (float)(bv - (double)bh); }
      float vhi = dmaxf(bh);
      float vlo = dmaxf(bh == vhi ? bl : NEGINF);
      bool elig = (bh == vhi) && (bl == vlo);
      u32 mc = elig ? (u32)((bjj << 6) | l) : 0xFFFFFFFFu;
      u32 mwin = wminu(mc);
      EK2 += __expf((float)(((double)vhi + (double)vlo) - qmaxd));
      if ((mwin & 63u) == (u32)l) kept2 |= 1u << (mwin >> 6);
    }
    const float inv2 = 1.0f / (EK2 + 1e-8f * Z2);
#pragma unroll
    for (int j = 0; j < 16; ++j)
      row[l + (j << 6)] = ((kept2 >> j) & 1u) ? (ev2[j] * inv2) : 0.0f;
  }
}

// ---------- kernel 4: fuse + edge MLP + head mean + sigmoid (fp32 io) ----------
__global__ __launch_bounds__(256) void k_fuse(const float* __restrict__ dyn,
                                              const float* __restrict__ stat,
                                              float* __restrict__ fin,
                                              const float* __restrict__ eW1,
                                              const float* __restrict__ eb1,
                                              const float* __restrict__ eW2,
                                              const float* __restrict__ eb2,
                                              const float* __restrict__ fwp) {
  const float w = fwp[0];
  const float w1 = 1.0f - w;
  float W1[4][8], B1v[8], W2v[8];
#pragma unroll
  for (int hh = 0; hh < 4; ++hh)
#pragma unroll
    for (int j = 0; j < 8; ++j) W1[hh][j] = eW1[hh * 8 + j];
#pragma unroll
  for (int j = 0; j < 8; ++j) { B1v[j] = eb1[j]; W2v[j] = eW2[j]; }
  const float b2 = eb2[0];

  const int i = blockIdx.x * 256 + threadIdx.x;   // [0, 4194304) float4s
  const int b = i >> 18;
  const int rem = i & 262143;
  const int n = rem >> 8;
  const int c4 = rem & 255;

  float fx[4][4];
#pragma unroll
  for (int hh = 0; hh < 4; ++hh) {
    float4 fd = ((const float4*)dyn)[(((size_t)((b * 4 + hh) * 1024 + n)) << 8) + c4];
    float4 fs = ((const float4*)stat)[(((size_t)(hh * 1024 + n)) << 8) + c4];
    fx[hh][0] = w1 * fs.x + w * fd.x;
    fx[hh][1] = w1 * fs.y + w * fd.y;
    fx[hh][2] = w1 * fs.z + w * fd.z;
    fx[hh][3] = w1 * fs.w + w * fd.w;
  }
  float ov[4];
#pragma unroll
  for (int x = 0; x < 4; ++x) {
    float ew = b2;
#pragma unroll
    for (int j = 0; j < 8; ++j) {
      float hj = B1v[j];
#pragma unroll
      for (int hh = 0; hh < 4; ++hh) hj = fmaf(fx[hh][x], W1[hh][j], hj);
      ew = fmaf(fmaxf(hj, 0.0f), W2v[j], ew);
    }
    float mean = (fx[0][x] + fx[1][x] + fx[2][x] + fx[3][x]) * 0.25f;
    float sg = 1.0f / (1.0f + __expf(-ew));
    ov[x] = sg * mean;
  }
  float4 o;
  o.x = ov[0]; o.y = ov[1]; o.z = ov[2]; o.w = ov[3];
  ((float4*)fin)[i] = o;
}

// ---------- launch ----------
extern "C" void kernel_launch(void* const* d_in, const int* in_sizes, int n_in,
                              void* d_out, int out_size, void* d_ws, size_t ws_size,
                              hipStream_t stream) {
  const float* pf   = (const float*)d_in[0];
  const float* E1   = (const float*)d_in[1];
  const float* E2   = (const float*)d_in[2];
  const float* temp = (const float*)d_in[3];
  const float* fw   = (const float*)d_in[4];
  const float* dW1  = (const float*)d_in[5];
  const float* db1  = (const float*)d_in[6];
  const float* ln_g = (const float*)d_in[7];
  const float* ln_b = (const float*)d_in[8];
  const float* dW2  = (const float*)d_in[9];
  const float* db2  = (const float*)d_in[10];
  const float* eW1  = (const float*)d_in[11];
  const float* eb1  = (const float*)d_in[12];
  const float* eW2  = (const float*)d_in[13];
  const float* eb2  = (const float*)d_in[14];

  // outputs are fp32, concatenated flat
  float* out_final = (float*)d_out;                              // 16,777,216 f
  float* out_stat  = out_final + (size_t)Bn * Nn * Nn;           // + 4,194,304 f
  float* out_dyn   = out_stat + (size_t)4 * Nn * Nn;             // +67,108,864 f

  // scratch inside final region (k_fuse, launched last, overwrites it):
  double* embD = (double*)d_out;                 // floats [0 .. 2,097,152)
  float* embF = out_final + 2097152;             // floats [2,097,152 .. 3,145,728)
  float* E2T  = out_final + 3145728;             // floats [3,145,728 .. 3,407,872)

  k_e2t<<<128, 256, 0, stream>>>(E2, E2T);
  k_meanmlp<<<Bn * Nn, 128, 0, stream>>>(pf, dW1, db1, ln_g, ln_b, dW2, db2, embD, embF);
  k_dot<0><<<256, 512, 0, stream>>>(E1, nullptr, E2, temp, out_stat);
  k_sel<0><<<1024, 256, 0, stream>>>(E1, nullptr, E2T, temp, out_stat);
  k_dot<1><<<4096, 512, 0, stream>>>(nullptr, embF, E2, temp, out_dyn);
  k_sel<1><<<16384, 256, 0, stream>>>(nullptr, embD, E2T, temp, out_dyn);
  k_fuse<<<16384, 256, 0, stream>>>(out_dyn, out_stat, out_final, eW1, eb1, eW2, eb2, fw);
}

// Round 10
// 542.659 us; speedup vs baseline: 1.8680x; 1.0852x over previous
//
#include <hip/hip_runtime.h>

typedef unsigned int u32;
typedef unsigned long long u64;

#define Bn 16
#define Nn 1024
#define Pp 72
#define MARG 3e-4f

#define NEGINF __int_as_float(0xff800000)
#define POSINF __int_as_float(0x7f800000)

// ---------- DPP wave-64 reductions (VALU-only) ----------
#define DPP_STEP(OP, CTRL, RM)                                                 \
  y = __builtin_amdgcn_update_dpp(__float_as_int(v), __float_as_int(v),        \
                                  CTRL, RM, 0xf, false);                       \
  v = OP(v, __int_as_float(y));

#define DPP_RED(NAME, OP)                                                      \
  __device__ __forceinline__ float NAME(float v) {                             \
    int y;                                                                     \
    DPP_STEP(OP, 0x111, 0xf)                                                   \
    DPP_STEP(OP, 0x112, 0xf)                                                   \
    DPP_STEP(OP, 0x114, 0xf)                                                   \
    DPP_STEP(OP, 0x118, 0xf)                                                   \
    DPP_STEP(OP, 0x142, 0xa)                                                   \
    DPP_STEP(OP, 0x143, 0xc)                                                   \
    return __int_as_float(__builtin_amdgcn_readlane(__float_as_int(v), 63));   \
  }

#define FADDOP(a, b) ((a) + (b))
DPP_RED(dmaxf, fmaxf)
DPP_RED(dminf, fminf)
DPP_RED(dsumf, FADDOP)

__device__ __forceinline__ u32 wminu(u32 v) {
#pragma unroll
  for (int off = 1; off < 64; off <<= 1) {
    u32 o = (u32)__shfl_xor((int)v, off, 64);
    v = (o < v) ? o : v;
  }
  return v;
}

// ---------- shared selection: top-16 of q[16]-per-lane, renormalized ----------
// q: logits (>=0). v: output sparse values. l: lane. rescore via fp64 (rare).
template <int MODE>
__device__ __forceinline__ void select_row(const float* __restrict__ q,
                                           float* __restrict__ v, int l,
                                           const float* __restrict__ e1row,
                                           const double* __restrict__ edrow,
                                           const float* __restrict__ e2t,
                                           double Td) {
  float lm = q[0];
#pragma unroll
  for (int j = 1; j < 16; ++j) lm = fmaxf(lm, q[j]);
  const float qmax = dmaxf(lm);

  // bit-bisection for the 16th largest (q >= 0 -> float bits uint-ordered)
  u32 lo = 0u, hi = __float_as_uint(qmax) + 1u;
  u32 kept = 0u;
  bool f16 = false;
  float pvf = 0.0f;
#pragma unroll 1
  while (hi - lo > 1u) {
    u32 mid = (lo + hi) >> 1;
    float pv = __uint_as_float(mid);
    u32 cw = 0;
#pragma unroll
    for (int j = 0; j < 16; ++j)
      cw += (u32)__popcll(__ballot(q[j] >= pv));
    if (cw >= 16u) lo = mid; else hi = mid;
    if (cw == 16u) { f16 = true; pvf = pv; break; }
  }
  float theta, ub;
  if (f16) {
    float vmin = POSINF, umax = -1.0f;
#pragma unroll
    for (int j = 0; j < 16; ++j) {
      if (q[j] >= pvf) { kept |= 1u << j; vmin = fminf(vmin, q[j]); }
      else umax = fmaxf(umax, q[j]);
    }
    theta = dminf(vmin);   // 16th value
    ub = dmaxf(umax);      // 17th value
  } else {
    theta = __uint_as_float(lo);
    u32 cw = 0;
#pragma unroll
    for (int j = 0; j < 16; ++j) {
      cw += (u32)__popcll(__ballot(q[j] > theta));
      if (q[j] > theta) kept |= 1u << j;
    }
    int rr = 16 - (int)cw;
#pragma unroll 1
    for (int it = 0; it < rr; ++it) {
      u32 mc = 0xFFFFFFFFu;
#pragma unroll
      for (int j = 0; j < 16; ++j)
        if (q[j] == theta && !((kept >> j) & 1u)) {
          u32 cc = (u32)((j << 6) | l);
          mc = cc < mc ? cc : mc;
        }
      u32 wm = wminu(mc);
      if ((wm & 63u) == (u32)l) kept |= 1u << (wm >> 6);
    }
    ub = theta;  // gap 0 -> rescore
  }

  if (theta - ub >= MARG) {
    float e[16];
    float es = 0.0f, ek = 0.0f;
#pragma unroll
    for (int j = 0; j < 16; ++j) {
      e[j] = __expf(q[j] - qmax);
      es += e[j];
      if ((kept >> j) & 1u) ek += e[j];
    }
    const float Z = dsumf(es);
    const float EK = dsumf(ek);
    const float inv = 1.0f / (EK + 1e-8f * Z);
#pragma unroll
    for (int j = 0; j < 16; ++j)
      v[j] = ((kept >> j) & 1u) ? (e[j] * inv) : 0.0f;
  } else {
    // rescore path (rare): fp64 for boundary-adjacent cols
    double qd[16];
    const float thr = ub - MARG;
#pragma unroll 1
    for (int j = 0; j < 16; ++j) {
      if (q[j] >= thr) {
        const int m = l + (j << 6);
        const float* col = e2t + (size_t)m * 64;
        double a = 0.0;
        for (int d = 0; d < 64; ++d) {
          double s = (MODE == 0) ? (double)e1row[d] : edrow[d];
          a = fma(s, (double)col[d], a);
        }
        qd[j] = (a > 0.0 ? a : 0.0) / Td;
      } else {
        qd[j] = (double)q[j];
      }
    }
    double bm = qd[0];
#pragma unroll
    for (int j = 1; j < 16; ++j) bm = qd[j] > bm ? qd[j] : bm;
    float mh = (float)bm;
    float mlo = (float)(bm - (double)mh);
    float whi = dmaxf(mh);
    float wlo = dmaxf(mh == whi ? mlo : NEGINF);
    const double qmaxd = (double)whi + (double)wlo;

    float ev2[16];
    float es2 = 0.0f;
#pragma unroll
    for (int j = 0; j < 16; ++j) { ev2[j] = __expf((float)(qd[j] - qmaxd)); es2 += ev2[j]; }
    const float Z2 = dsumf(es2);

    u32 kept2 = 0;
    float EK2 = 0.0f;
#pragma unroll 1
    for (int it = 0; it < 16; ++it) {
      double bv = -1.0;
      int bjj = -1;
#pragma unroll
      for (int j = 0; j < 16; ++j) {
        bool tk = (((kept2 >> j) & 1u) == 0u) && (qd[j] > bv);
        bv = tk ? qd[j] : bv;
        bjj = tk ? j : bjj;
      }
      float bh = NEGINF, bl = NEGINF;
      if (bjj >= 0) { bh = (float)bv; bl = (float)(bv - (double)bh); }
      float vhi = dmaxf(bh);
      float vlo = dmaxf(bh == vhi ? bl : NEGINF);
      bool elig = (bh == vhi) && (bl == vlo);
      u32 mc = elig ? (u32)((bjj << 6) | l) : 0xFFFFFFFFu;
      u32 mwin = wminu(mc);
      EK2 += __expf((float)(((double)vhi + (double)vlo) - qmaxd));
      if ((mwin & 63u) == (u32)l) kept2 |= 1u << (mwin >> 6);
    }
    const float inv2 = 1.0f / (EK2 + 1e-8f * Z2);
#pragma unroll
    for (int j = 0; j < 16; ++j)
      v[j] = ((kept2 >> j) & 1u) ? (ev2[j] * inv2) : 0.0f;
  }
}

// ---------- kernel 0: E2 transpose (per head): E2T[h][m][d] = E2[h][d][m] ----------
__global__ __launch_bounds__(256) void k_e2t(const float* __restrict__ E2,
                                             float* __restrict__ E2T) {
  __shared__ float tile[32][65];
  const int h = blockIdx.x >> 5;
  const int m0 = (blockIdx.x & 31) << 5;
  const float* src = E2 + (size_t)h * 65536;
  float* dst = E2T + (size_t)h * 65536;
  const int t = threadIdx.x;
#pragma unroll
  for (int k = 0; k < 8; ++k) {
    int idx = k * 256 + t;
    int d = idx >> 5, mm = idx & 31;
    tile[mm][d] = src[d * 1024 + m0 + mm];
  }
  __syncthreads();
#pragma unroll
  for (int k = 0; k < 8; ++k) {
    int idx = k * 256 + t;
    int mm = idx >> 6, d = idx & 63;
    dst[(size_t)(m0 + mm) * 64 + d] = tile[mm][d];
  }
}

// ---------- kernel 1: fused mean-over-P + node MLP (fp64), emits fp64+fp32 ----------
__global__ __launch_bounds__(128) void k_meanmlp(const float* __restrict__ pf,
                                                 const float* __restrict__ dW1,
                                                 const float* __restrict__ db1,
                                                 const float* __restrict__ ln_g,
                                                 const float* __restrict__ ln_b,
                                                 const float* __restrict__ dW2,
                                                 const float* __restrict__ db2,
                                                 double* __restrict__ embD,
                                                 float* __restrict__ embF) {
  __shared__ double ndD[96];
  __shared__ double red[64];
  __shared__ double h1r[64];
  const int t = threadIdx.x;
  const int bn = blockIdx.x;

  if (t < 96) {
    const float* src = pf + (size_t)bn * (Pp * 96) + t;
    double s = 0.0;
    for (int p = 0; p < Pp; ++p) s += (double)src[p * 96];
    ndD[t] = s / 72.0;
  }
  __syncthreads();

  double a = 0.0;
  if (t < 64) {
    a = (double)db1[t];
    for (int d = 0; d < 96; ++d) a = fma(ndD[d], (double)dW1[d * 64 + t], a);
    red[t] = a;
  }
  __syncthreads();
  for (int s2 = 32; s2 >= 1; s2 >>= 1) {
    if (t < s2) red[t] += red[t + s2];
    __syncthreads();
  }
  const double mu = red[0] * (1.0 / 64.0);
  __syncthreads();
  const double dv = a - mu;
  if (t < 64) red[t] = dv * dv;
  __syncthreads();
  for (int s2 = 32; s2 >= 1; s2 >>= 1) {
    if (t < s2) red[t] += red[t + s2];
    __syncthreads();
  }
  const double var = red[0] * (1.0 / 64.0);
  if (t < 64) {
    double xn = dv / sqrt(var + 1e-5) * (double)ln_g[t] + (double)ln_b[t];
    h1r[t] = xn > 0.0 ? xn : 0.0;
  }
  __syncthreads();
  if (t < 64) {
    double e = (double)db2[t];
    for (int k = 0; k < 64; ++k) e = fma(h1r[k], (double)dW2[k * 64 + t], e);
    embD[(size_t)bn * 64 + t] = e;
    embF[(size_t)bn * 64 + t] = (float)e;
  }
}

// ---------- kernel 2: DOT — 16 rows/block, 8 cols/thread, logits to global ----------
// per-column fp32 fma order (d ascending) identical to prior rounds -> bit-identical.
template <int MODE>
__global__ __launch_bounds__(256) void k_dot(const float* __restrict__ e1f,
                                             const float* __restrict__ embF,
                                             const float* __restrict__ E2,
                                             const float* __restrict__ temp,
                                             float* __restrict__ outp) {
  __shared__ float embsh[64][16];
  const int t = threadIdx.x;
  const int r0 = blockIdx.x * 16;   // 16 rows per block, same head
  int h;
  size_t erow;
  if (MODE == 0) {
    h = r0 >> 10;
    erow = (size_t)r0;
  } else {
    int b = r0 >> 12;
    h = (r0 >> 10) & 3;
    int n0 = r0 & 1023;
    erow = (size_t)(b << 10) + n0;
  }
  const float* efa = (MODE == 0) ? (e1f + erow * 64) : (embF + erow * 64);
  const float* e2 = E2 + (size_t)h * 65536;
  const float invT = 1.0f / temp[h];

  // stage emb fp32 into LDS (transposed [d][g]); 1024 elems by 256 threads
#pragma unroll
  for (int i = t; i < 1024; i += 256) {
    int g = i & 15, d = i >> 4;
    embsh[d][g] = efa[g * 64 + d];
  }
  __syncthreads();

  const int s = t >> 7;          // row subgroup: rows 8s .. 8s+7
  const int c1 = (t & 127) * 4;  // first col quad
  const int c2 = c1 + 512;       // second col quad

  float acc[8][8];
#pragma unroll
  for (int g = 0; g < 8; ++g)
#pragma unroll
    for (int x = 0; x < 8; ++x) acc[g][x] = 0.0f;

#pragma unroll 4
  for (int d = 0; d < 64; ++d) {
    float4 va = *(const float4*)(e2 + d * 1024 + c1);
    float4 vb = *(const float4*)(e2 + d * 1024 + c2);
    float4 ea = *(const float4*)&embsh[d][8 * s];
    float4 eb = *(const float4*)&embsh[d][8 * s + 4];
    float sg;
#define ROWFMA(g, SS)                                                          \
    sg = SS;                                                                   \
    acc[g][0] = fmaf(sg, va.x, acc[g][0]);                                     \
    acc[g][1] = fmaf(sg, va.y, acc[g][1]);                                     \
    acc[g][2] = fmaf(sg, va.z, acc[g][2]);                                     \
    acc[g][3] = fmaf(sg, va.w, acc[g][3]);                                     \
    acc[g][4] = fmaf(sg, vb.x, acc[g][4]);                                     \
    acc[g][5] = fmaf(sg, vb.y, acc[g][5]);                                     \
    acc[g][6] = fmaf(sg, vb.z, acc[g][6]);                                     \
    acc[g][7] = fmaf(sg, vb.w, acc[g][7]);
    ROWFMA(0, ea.x) ROWFMA(1, ea.y) ROWFMA(2, ea.z) ROWFMA(3, ea.w)
    ROWFMA(4, eb.x) ROWFMA(5, eb.y) ROWFMA(6, eb.z) ROWFMA(7, eb.w)
#undef ROWFMA
  }

#pragma unroll
  for (int g = 0; g < 8; ++g) {
    float* orow = outp + (size_t)(r0 + 8 * s + g) * 1024;
    float4 o1, o2;
    o1.x = fmaxf(acc[g][0], 0.0f) * invT;
    o1.y = fmaxf(acc[g][1], 0.0f) * invT;
    o1.z = fmaxf(acc[g][2], 0.0f) * invT;
    o1.w = fmaxf(acc[g][3], 0.0f) * invT;
    o2.x = fmaxf(acc[g][4], 0.0f) * invT;
    o2.y = fmaxf(acc[g][5], 0.0f) * invT;
    o2.z = fmaxf(acc[g][6], 0.0f) * invT;
    o2.w = fmaxf(acc[g][7], 0.0f) * invT;
    *(float4*)(orow + c1) = o1;
    *(float4*)(orow + c2) = o2;
  }
}

// ---------- kernel 3: SELECT (static rows) — 1 row/wave, in-place ----------
__global__ __launch_bounds__(256) void k_sel0(const float* __restrict__ E1,
                                              const float* __restrict__ E2T,
                                              const float* __restrict__ temp,
                                              float* __restrict__ outp) {
  const int t = threadIdx.x;
  const int w = t >> 6, l = t & 63;
  const int r = blockIdx.x * 4 + w;
  const int h = r >> 10;
  const float* e2t = E2T + (size_t)h * 65536;
  const double Td = (double)temp[h];
  float* row = outp + (size_t)r * 1024;

  float q[16], v[16];
#pragma unroll
  for (int j = 0; j < 16; ++j) q[j] = row[l + (j << 6)];
  select_row<0>(q, v, l, E1 + (size_t)r * 64, nullptr, e2t, Td);
#pragma unroll
  for (int j = 0; j < 16; ++j) row[l + (j << 6)] = v[j];
}

// ---------- kernel 4: SELECT dyn + fuse + edge MLP + final (per (b,n)) ----------
__global__ __launch_bounds__(256) void k_selfuse(float* __restrict__ dyn,
                                                 const float* __restrict__ stat,
                                                 float* __restrict__ fin,
                                                 const double* __restrict__ embD,
                                                 const float* __restrict__ E2T,
                                                 const float* __restrict__ temp,
                                                 const float* __restrict__ eW1,
                                                 const float* __restrict__ eb1,
                                                 const float* __restrict__ eW2,
                                                 const float* __restrict__ eb2,
                                                 const float* __restrict__ fwp) {
  __shared__ float rowbuf[4][1024];   // sparse dyn values, one row per head
  const int t = threadIdx.x;
  const int w = t >> 6, l = t & 63;   // wave w = head w
  const int bn = blockIdx.x;
  const int b = bn >> 10, n = bn & 1023;

  // --- selection phase: wave w sparsifies dyn[b, w, n, :] ---
  {
    const int h = w;
    float* row = dyn + (((size_t)((b * 4 + h) * 1024 + n)) << 10);
    const float* e2t = E2T + (size_t)h * 65536;
    const double Td = (double)temp[h];
    float q[16], v[16];
#pragma unroll
    for (int j = 0; j < 16; ++j) q[j] = row[l + (j << 6)];
    select_row<1>(q, v, l, nullptr, embD + (((size_t)(b << 10) + n) << 6), e2t, Td);
#pragma unroll
    for (int j = 0; j < 16; ++j) rowbuf[h][l + (j << 6)] = v[j];
  }
  __syncthreads();

  // --- write sparse dyn rows (coalesced float4) ---
#pragma unroll
  for (int k = 0; k < 4; ++k) {
    int idx = t + 256 * k;            // 1024 float4 slots
    int h2 = idx >> 8, c4 = idx & 255;
    float* drow = dyn + (((size_t)((b * 4 + h2) * 1024 + n)) << 10);
    *(float4*)(drow + c4 * 4) = *(const float4*)&rowbuf[h2][c4 * 4];
  }

  // --- fuse + edge MLP + head-mean + sigmoid for final[b, n, :] ---
  const float fw = fwp[0];
  const float w1 = 1.0f - fw;
  float W1[4][8], B1v[8], W2v[8];
#pragma unroll
  for (int hh = 0; hh < 4; ++hh)
#pragma unroll
    for (int j = 0; j < 8; ++j) W1[hh][j] = eW1[hh * 8 + j];
#pragma unroll
  for (int j = 0; j < 8; ++j) { B1v[j] = eb1[j]; W2v[j] = eW2[j]; }
  const float b2 = eb2[0];

  float fx[4][4];
#pragma unroll
  for (int hh = 0; hh < 4; ++hh) {
    float4 fd = *(const float4*)&rowbuf[hh][t * 4];
    float4 fs = *(const float4*)(stat + (((size_t)(hh * 1024 + n)) << 10) + t * 4);
    fx[hh][0] = w1 * fs.x + fw * fd.x;
    fx[hh][1] = w1 * fs.y + fw * fd.y;
    fx[hh][2] = w1 * fs.z + fw * fd.z;
    fx[hh][3] = w1 * fs.w + fw * fd.w;
  }
  float ov[4];
#pragma unroll
  for (int x = 0; x < 4; ++x) {
    float ew = b2;
#pragma unroll
    for (int j = 0; j < 8; ++j) {
      float hj = B1v[j];
#pragma unroll
      for (int hh = 0; hh < 4; ++hh) hj = fmaf(fx[hh][x], W1[hh][j], hj);
      ew = fmaf(fmaxf(hj, 0.0f), W2v[j], ew);
    }
    float mean = (fx[0][x] + fx[1][x] + fx[2][x] + fx[3][x]) * 0.25f;
    float sg = 1.0f / (1.0f + __expf(-ew));
    ov[x] = sg * mean;
  }
  float4 o;
  o.x = ov[0]; o.y = ov[1]; o.z = ov[2]; o.w = ov[3];
  *(float4*)(fin + (size_t)b * 1048576 + (size_t)n * 1024 + t * 4) = o;
}

// ---------- launch ----------
extern "C" void kernel_launch(void* const* d_in, const int* in_sizes, int n_in,
                              void* d_out, int out_size, void* d_ws, size_t ws_size,
                              hipStream_t stream) {
  const float* pf   = (const float*)d_in[0];
  const float* E1   = (const float*)d_in[1];
  const float* E2   = (const float*)d_in[2];
  const float* temp = (const float*)d_in[3];
  const float* fw   = (const float*)d_in[4];
  const float* dW1  = (const float*)d_in[5];
  const float* db1  = (const float*)d_in[6];
  const float* ln_g = (const float*)d_in[7];
  const float* ln_b = (const float*)d_in[8];
  const float* dW2  = (const float*)d_in[9];
  const float* db2  = (const float*)d_in[10];
  const float* eW1  = (const float*)d_in[11];
  const float* eb1  = (const float*)d_in[12];
  const float* eW2  = (const float*)d_in[13];
  const float* eb2  = (const float*)d_in[14];

  // outputs are fp32, concatenated flat
  float* out_final = (float*)d_out;                              // 16,777,216 f
  float* out_stat  = out_final + (size_t)Bn * Nn * Nn;           // + 4,194,304 f
  float* out_dyn   = out_stat + (size_t)4 * Nn * Nn;             // +67,108,864 f

  // scratch in d_ws (~1.8 GB available; we use 13 MB)
  double* embD = (double*)d_ws;                                  // 8 MB
  float* embF  = (float*)((char*)d_ws + (8u << 20));             // 4 MB
  float* E2T   = (float*)((char*)d_ws + (12u << 20));            // 1 MB

  k_e2t<<<128, 256, 0, stream>>>(E2, E2T);
  k_meanmlp<<<Bn * Nn, 128, 0, stream>>>(pf, dW1, db1, ln_g, ln_b, dW2, db2, embD, embF);
  k_dot<0><<<256, 256, 0, stream>>>(E1, nullptr, E2, temp, out_stat);
  k_sel0<<<1024, 256, 0, stream>>>(E1, E2T, temp, out_stat);
  k_dot<1><<<4096, 256, 0, stream>>>(nullptr, embF, E2, temp, out_dyn);
  k_selfuse<<<16384, 256, 0, stream>>>(out_dyn, out_stat, out_final, embD, E2T,
                                       temp, eW1, eb1, eW2, eb2, fw);
}